// Round 1
// baseline (1023.204 us; speedup 1.0000x reference)
//
#include <hip/hip_runtime.h>
#include <math.h>

// Problem constants
#define D_   2048
#define H_   512
#define K2D  4096
#define X_   36
#define NCOL 1152   // N * Y = 32*36

// ws layout (float offsets). Zero region first (atomicAdd targets).
#define O_H1    0u
#define O_H2    262144u
#define O_TPROJ 524288u
#define O_S     1703936u
#define O_CAT   2367488u
#define O_TW    4464640u
#define O_DW    4483072u
#define O_SB    4501504u
#define O_SO    4502016u
#define ZERO_BYTES (2367488ull * 4ull)

// B-tile LDS mapping: 32 chunks of 4 floats per k-row, +16B pad every 8 chunks
// so lane chunk-stride-2 reads land 2-way per bank (free per m136).
__device__ __forceinline__ int bmap(int kk, int ch) {
  return kk * 144 + (ch << 2) + ((ch >> 3) << 2);
}

// ---------------------------------------------------------------------------
// Generic fp32 GEMM, C += A@B. 128x128 tile, 256 thr, 8x8 micro (rows strided
// by 16 for LDS bank spread). amode=1: A rows are concat(fc_t[row/32], fc_d[row]).
// ---------------------------------------------------------------------------
__global__ __launch_bounds__(256, 1) void gemm128(
    const float* __restrict__ A, const float* __restrict__ A2,
    const float* __restrict__ Bm, float* __restrict__ C,
    int M, int N, int K, int kchunk, int amode)
{
  __shared__ float As[128 * 20];
  __shared__ float Bs[16 * 144];
  const int t  = threadIdx.x;
  const int m0 = blockIdx.y << 7;
  const int n0 = blockIdx.x << 7;
  const int k0 = blockIdx.z * kchunk;
  const int r0 = t >> 4;             // micro rows r0 + 16*i
  const int c0 = (t & 15) << 3;      // micro cols c0 .. c0+7
  float acc[64];
  #pragma unroll
  for (int i = 0; i < 64; i++) acc[i] = 0.f;

  for (int kb = k0; kb < k0 + kchunk; kb += 16) {
    __syncthreads();
    // stage A tile: 128 rows x 16 k  (512 float4)
    #pragma unroll
    for (int q = 0; q < 2; q++) {
      int idx = t + (q << 8);
      int row = idx >> 2;
      int c4  = (idx & 3) << 2;
      int gr  = m0 + row;
      int gk  = kb + c4;
      float4 v = make_float4(0.f, 0.f, 0.f, 0.f);
      if (gr < M) {
        const float* src;
        if (amode == 0) src = A + (size_t)gr * K + gk;
        else src = (gk < 2048) ? (A  + ((size_t)(gr >> 5) << 11) + gk)
                               : (A2 + ((size_t)gr << 11) + (gk - 2048));
        v = *(const float4*)src;
      }
      *(float4*)&As[row * 20 + c4] = v;
    }
    // stage B tile: 16 k x 128 cols, k-major padded layout
    #pragma unroll
    for (int q = 0; q < 2; q++) {
      int idx = t + (q << 8);
      int kk  = idx >> 5;
      int cq  = (idx & 31) << 2;
      float4 v = *(const float4*)(Bm + (size_t)(kb + kk) * N + n0 + cq);
      *(float4*)&Bs[bmap(kk, cq >> 2)] = v;
    }
    __syncthreads();
    #pragma unroll
    for (int kk4 = 0; kk4 < 16; kk4 += 4) {
      float4 a4[8];
      #pragma unroll
      for (int i = 0; i < 8; i++)
        a4[i] = *(const float4*)&As[(r0 + (i << 4)) * 20 + kk4];
      #pragma unroll
      for (int e = 0; e < 4; e++) {
        int kk = kk4 + e;
        float4 b0 = *(const float4*)&Bs[bmap(kk, (c0 >> 2))];
        float4 b1 = *(const float4*)&Bs[bmap(kk, (c0 >> 2) + 1)];
        float bv[8] = {b0.x, b0.y, b0.z, b0.w, b1.x, b1.y, b1.z, b1.w};
        #pragma unroll
        for (int i = 0; i < 8; i++) {
          float a = (e == 0) ? a4[i].x : (e == 1) ? a4[i].y : (e == 2) ? a4[i].z : a4[i].w;
          #pragma unroll
          for (int j = 0; j < 8; j++)
            acc[i * 8 + j] = fmaf(a, bv[j], acc[i * 8 + j]);
        }
      }
    }
  }
  #pragma unroll
  for (int i = 0; i < 8; i++) {
    int gr = m0 + r0 + (i << 4);
    if (gr < M) {
      #pragma unroll
      for (int j = 0; j < 8; j++)
        atomicAdd(&C[(size_t)gr * N + n0 + c0 + j], acc[i * 8 + j]);
    }
  }
}

// ---------------------------------------------------------------------------
// S[b, x, col] += tproj[b,x,:] . att_d[b,col,:]   (A @ B^T, both k-contiguous)
// 64x128 tile (rows 36..63 wasted), 128 thr, 8x8 micro. Stores scattered into
// inners layout [b][i][x][y] with col = i*36+y.
// ---------------------------------------------------------------------------
__global__ __launch_bounds__(128, 1) void sgemm36(
    const float* __restrict__ tproj, const float* __restrict__ attd,
    float* __restrict__ Sbuf, int kchunk)
{
  __shared__ float As[64 * 20];
  __shared__ float Bs[16 * 144];
  const int t  = threadIdx.x;
  const int n0 = blockIdx.x << 7;
  const int b  = blockIdx.y;
  const int k0 = blockIdx.z * kchunk;
  const int r0 = t >> 4;            // micro rows r0 + 8*i
  const int c0 = (t & 15) << 3;
  const float* Ab = tproj + (size_t)b * X_ * D_;
  const float* Bb = attd  + (size_t)b * NCOL * D_;
  float acc[64];
  #pragma unroll
  for (int i = 0; i < 64; i++) acc[i] = 0.f;

  for (int kb = k0; kb < k0 + kchunk; kb += 16) {
    __syncthreads();
    // stage A: 64 rows x 16 k (rows >= 36 zero)
    #pragma unroll
    for (int q = 0; q < 2; q++) {
      int idx = t + (q << 7);
      int row = idx >> 2;
      int c4  = (idx & 3) << 2;
      float4 v = make_float4(0.f, 0.f, 0.f, 0.f);
      if (row < X_) v = *(const float4*)(Ab + (size_t)row * D_ + kb + c4);
      *(float4*)&As[row * 20 + c4] = v;
    }
    // stage B^T: att_d rows are k-contiguous -> transpose on LDS store
    #pragma unroll
    for (int q = 0; q < 4; q++) {
      int idx = t + (q << 7);
      int col = idx >> 2;
      int kq  = (idx & 3) << 2;
      float4 v = *(const float4*)(Bb + (size_t)(n0 + col) * D_ + kb + kq);
      Bs[bmap(kq + 0, col >> 2) + (col & 3)] = v.x;
      Bs[bmap(kq + 1, col >> 2) + (col & 3)] = v.y;
      Bs[bmap(kq + 2, col >> 2) + (col & 3)] = v.z;
      Bs[bmap(kq + 3, col >> 2) + (col & 3)] = v.w;
    }
    __syncthreads();
    #pragma unroll
    for (int kk4 = 0; kk4 < 16; kk4 += 4) {
      float4 a4[8];
      #pragma unroll
      for (int i = 0; i < 8; i++)
        a4[i] = *(const float4*)&As[(r0 + (i << 3)) * 20 + kk4];
      #pragma unroll
      for (int e = 0; e < 4; e++) {
        int kk = kk4 + e;
        float4 b0 = *(const float4*)&Bs[bmap(kk, (c0 >> 2))];
        float4 b1 = *(const float4*)&Bs[bmap(kk, (c0 >> 2) + 1)];
        float bv[8] = {b0.x, b0.y, b0.z, b0.w, b1.x, b1.y, b1.z, b1.w};
        #pragma unroll
        for (int i = 0; i < 8; i++) {
          float a = (e == 0) ? a4[i].x : (e == 1) ? a4[i].y : (e == 2) ? a4[i].z : a4[i].w;
          #pragma unroll
          for (int j = 0; j < 8; j++)
            acc[i * 8 + j] = fmaf(a, bv[j], acc[i * 8 + j]);
        }
      }
    }
  }
  #pragma unroll
  for (int i = 0; i < 8; i++) {
    int x = r0 + (i << 3);
    if (x < X_) {
      #pragma unroll
      for (int j = 0; j < 8; j++) {
        int col = n0 + c0 + j;
        int ii  = col / 36;
        int y   = col - ii * 36;
        atomicAdd(&Sbuf[(((size_t)b * 32 + ii) * 36 + x) * 36 + y], acc[i * 8 + j]);
      }
    }
  }
}

// ---------------------------------------------------------------------------
// scores[row] = relu(h[row,:] + b1) . W2 + b2
// ---------------------------------------------------------------------------
__global__ __launch_bounds__(256) void mlp_tail(
    const float* __restrict__ hbuf, const float* __restrict__ b1,
    const float* __restrict__ w2, const float* __restrict__ b2,
    float* __restrict__ out)
{
  int row = blockIdx.x;
  int t   = threadIdx.x;
  float v = 0.f;
  #pragma unroll
  for (int q = 0; q < 2; q++) {
    int h = t + (q << 8);
    float x = hbuf[(size_t)row * H_ + h] + b1[h];
    v += fmaxf(x, 0.f) * w2[h];
  }
  #pragma unroll
  for (int off = 32; off > 0; off >>= 1) v += __shfl_down(v, off, 64);
  __shared__ float red[4];
  if ((t & 63) == 0) red[t >> 6] = v;
  __syncthreads();
  if (t == 0) out[row] = red[0] + red[1] + red[2] + red[3] + b2[0];
}

// ---------------------------------------------------------------------------
// Per (b,i): mask S, row/col max, two softmaxes -> tw[36], dw[36]
// ---------------------------------------------------------------------------
__global__ __launch_bounds__(64) void attn_weights(
    const float* __restrict__ Sbuf, const int* __restrict__ amt,
    const int* __restrict__ amd, float* __restrict__ tw, float* __restrict__ dw)
{
  __shared__ float Sm[36 * 37];
  __shared__ int   mtv[36], mdv[36];
  __shared__ float mrow[36], mcol[36];
  int bi = blockIdx.x;
  int b  = bi >> 5;
  int t  = threadIdx.x;
  if (t < 36) { mtv[t] = amt[b * 36 + t]; mdv[t] = amd[bi * 36 + t]; }
  __syncthreads();
  for (int idx = t; idx < 1296; idx += 64) {
    int x = idx / 36, y = idx - x * 36;
    float v = Sbuf[(size_t)bi * 1296 + idx];
    Sm[x * 37 + y] = (mtv[x] != 0 && mdv[y] != 0) ? v : -1e9f;
  }
  __syncthreads();
  if (t < 36) {
    float r = -INFINITY, c = -INFINITY;
    for (int k = 0; k < 36; k++) {
      r = fmaxf(r, Sm[t * 37 + k]);
      c = fmaxf(c, Sm[k * 37 + t]);
    }
    mrow[t] = r; mcol[t] = c;
  }
  __syncthreads();
  {
    float v = (t < 36) ? mrow[t] : -INFINITY;
    float m = v;
    #pragma unroll
    for (int off = 32; off > 0; off >>= 1) m = fmaxf(m, __shfl_xor(m, off, 64));
    float e = (t < 36) ? expf(v - m) : 0.f;
    float s = e;
    #pragma unroll
    for (int off = 32; off > 0; off >>= 1) s += __shfl_xor(s, off, 64);
    if (t < 36) tw[bi * 36 + t] = e / s;
  }
  {
    float v = (t < 36) ? mcol[t] : -INFINITY;
    float m = v;
    #pragma unroll
    for (int off = 32; off > 0; off >>= 1) m = fmaxf(m, __shfl_xor(m, off, 64));
    float e = (t < 36) ? expf(v - m) : 0.f;
    float s = e;
    #pragma unroll
    for (int off = 32; off > 0; off >>= 1) s += __shfl_xor(s, off, 64);
    if (t < 36) dw[bi * 36 + t] = e / s;
  }
}

// ---------------------------------------------------------------------------
// cat_att[bi] = [ sum_x tw[x]*att_t[b,x,:], sum_y dw[y]*att_d[bi,y,:] ]
// ---------------------------------------------------------------------------
__global__ __launch_bounds__(256) void wfeats(
    const float* __restrict__ attt, const float* __restrict__ attd,
    const float* __restrict__ tw, const float* __restrict__ dw,
    float* __restrict__ cat)
{
  __shared__ float twl[36], dwl[36];
  int bi = blockIdx.x, b = bi >> 5, t = threadIdx.x;
  if (t < 36) { twl[t] = tw[bi * 36 + t]; dwl[t] = dw[bi * 36 + t]; }
  __syncthreads();
  const float4* at4 = (const float4*)(attt + (size_t)b * X_ * D_);
  const float4* ad4 = (const float4*)(attd + (size_t)bi * X_ * D_);
  float4 t0 = make_float4(0, 0, 0, 0), t1 = t0, d0 = t0, d1 = t0;
  for (int x = 0; x < 36; x++) {
    float wt = twl[x], wd = dwl[x];
    float4 a  = at4[x * 512 + t];
    float4 a2 = at4[x * 512 + t + 256];
    float4 e  = ad4[x * 512 + t];
    float4 e2 = ad4[x * 512 + t + 256];
    t0.x = fmaf(wt, a.x, t0.x);  t0.y = fmaf(wt, a.y, t0.y);
    t0.z = fmaf(wt, a.z, t0.z);  t0.w = fmaf(wt, a.w, t0.w);
    t1.x = fmaf(wt, a2.x, t1.x); t1.y = fmaf(wt, a2.y, t1.y);
    t1.z = fmaf(wt, a2.z, t1.z); t1.w = fmaf(wt, a2.w, t1.w);
    d0.x = fmaf(wd, e.x, d0.x);  d0.y = fmaf(wd, e.y, d0.y);
    d0.z = fmaf(wd, e.z, d0.z);  d0.w = fmaf(wd, e.w, d0.w);
    d1.x = fmaf(wd, e2.x, d1.x); d1.y = fmaf(wd, e2.y, d1.y);
    d1.z = fmaf(wd, e2.z, d1.z); d1.w = fmaf(wd, e2.w, d1.w);
  }
  float4* c4 = (float4*)(cat + (size_t)bi * K2D);
  c4[t] = t0; c4[t + 256] = t1; c4[512 + t] = d0; c4[512 + t + 256] = d1;
}

// ---------------------------------------------------------------------------
// out[b,:] = log_softmax(sb + so) over N=32
// ---------------------------------------------------------------------------
__global__ __launch_bounds__(64) void lsm(
    const float* __restrict__ sb, const float* __restrict__ so,
    float* __restrict__ out)
{
  int b = blockIdx.x, t = threadIdx.x;
  float s = (t < 32) ? sb[b * 32 + t] + so[b * 32 + t] : -INFINITY;
  float m = s;
  #pragma unroll
  for (int off = 32; off > 0; off >>= 1) m = fmaxf(m, __shfl_xor(m, off, 64));
  float e = (t < 32) ? expf(s - m) : 0.f;
  float sum = e;
  #pragma unroll
  for (int off = 32; off > 0; off >>= 1) sum += __shfl_xor(sum, off, 64);
  if (t < 32) out[b * 32 + t] = s - m - logf(sum);
}

extern "C" void kernel_launch(void* const* d_in, const int* in_sizes, int n_in,
                              void* d_out, int out_size, void* d_ws, size_t ws_size,
                              hipStream_t stream)
{
  const float* fc_t  = (const float*)d_in[0];
  const float* fc_d  = (const float*)d_in[1];
  const float* att_t = (const float*)d_in[2];
  const float* att_d = (const float*)d_in[3];
  const int*   am_t  = (const int*)d_in[4];
  const int*   am_d  = (const int*)d_in[5];
  const float* W1    = (const float*)d_in[6];
  const float* b1    = (const float*)d_in[7];
  const float* W2    = (const float*)d_in[8];
  const float* b2    = (const float*)d_in[9];
  const float* Wbil  = (const float*)d_in[10];
  const float* oW1   = (const float*)d_in[11];
  const float* ob1   = (const float*)d_in[12];
  const float* oW2   = (const float*)d_in[13];
  const float* ob2   = (const float*)d_in[14];
  float* ws  = (float*)d_ws;
  float* out = (float*)d_out;

  // zero the atomicAdd targets (h1, h2, tproj, S)
  hipMemsetAsync(d_ws, 0, ZERO_BYTES, stream);

  // base scorer hidden: h1 += concat(fc_t, fc_d) @ W1
  gemm128<<<dim3(4, 4, 16), 256, 0, stream>>>(fc_t, fc_d, W1, ws + O_H1,
                                              512, 512, 4096, 256, 1);
  // tproj += att_t @ Wbil
  gemm128<<<dim3(16, 5, 8), 256, 0, stream>>>(att_t, nullptr, Wbil, ws + O_TPROJ,
                                              576, 2048, 2048, 256, 0);
  // base scores
  mlp_tail<<<512, 256, 0, stream>>>(ws + O_H1, b1, W2, b2, ws + O_SB);
  // inners
  sgemm36<<<dim3(9, 16, 2), 128, 0, stream>>>(ws + O_TPROJ, att_d, ws + O_S, 1024);
  // attention weights
  attn_weights<<<512, 64, 0, stream>>>(ws + O_S, am_t, am_d, ws + O_TW, ws + O_DW);
  // weighted features -> cat_att
  wfeats<<<512, 256, 0, stream>>>(att_t, att_d, ws + O_TW, ws + O_DW, ws + O_CAT);
  // object scorer hidden: h2 += cat_att @ oW1
  gemm128<<<dim3(4, 4, 16), 256, 0, stream>>>(ws + O_CAT, nullptr, oW1, ws + O_H2,
                                              512, 512, 4096, 256, 0);
  // object scores
  mlp_tail<<<512, 256, 0, stream>>>(ws + O_H2, ob1, oW2, ob2, ws + O_SO);
  // final log_softmax
  lsm<<<16, 64, 0, stream>>>(ws + O_SB, ws + O_SO, out);
}

// Round 2
// 544.277 us; speedup vs baseline: 1.8799x; 1.8799x over previous
//
#include <hip/hip_runtime.h>
#include <math.h>

// Problem constants
#define D_   2048
#define H_   512
#define K2D  4096
#define X_   36
#define NCOL 1152   // N * Y = 32*36

// Split-K factors (partials + fused reduce; NO atomics anywhere)
#define Z_MLP 16    // kchunk 256
#define Z_TP  4     // kchunk 512
#define Z_S   4     // kchunk 512

// ws layout (float offsets). Regions reused sequentially:
//  A: HP1 (z16 x 512x512 = 4194304) -> TPP (z4 x 576x2048 = 4718592)
//     -> SP (z4 x 16x36x1152 = 2654208) -> HP2 (4194304)
//  B: TPROJ (576x2048 = 1179648) -> CAT (512x4096 = 2097152)
#define O_A   0u
#define O_B   4718592u
#define O_TW  6815744u
#define O_DW  6834176u
#define O_SB  6852608u
#define O_SO  6853120u
// total 6853632 floats = 26.2 MB

#define SP_PLANE 663552u   // 16*36*1152 per z-plane

// B-tile LDS mapping: 32 chunks of 4 floats per k-row, +16B pad every 8 chunks
// so lane chunk-stride-2 reads land 2-way per bank (free per m136).
__device__ __forceinline__ int bmap(int kk, int ch) {
  return kk * 144 + (ch << 2) + ((ch >> 3) << 2);
}

// ---------------------------------------------------------------------------
// fp32 GEMM, Cpart[z] = A@B over this z's K-chunk. 128x128 tile, 256 thr,
// 8x8 micro (rows strided 16). Plain float4 stores to private partial buffer.
// amode=1: A rows are concat(fc_t[row/32], fc_d[row]).
// ---------------------------------------------------------------------------
__global__ __launch_bounds__(256, 1) void gemm_part(
    const float* __restrict__ A, const float* __restrict__ A2,
    const float* __restrict__ Bm, float* __restrict__ Cpart,
    int M, int N, int K, int kchunk, int amode)
{
  __shared__ float As[128 * 20];
  __shared__ float Bs[16 * 144];
  const int t  = threadIdx.x;
  const int m0 = blockIdx.y << 7;
  const int n0 = blockIdx.x << 7;
  const int k0 = blockIdx.z * kchunk;
  const int r0 = t >> 4;             // micro rows r0 + 16*i
  const int c0 = (t & 15) << 3;      // micro cols c0 .. c0+7
  float acc[64];
  #pragma unroll
  for (int i = 0; i < 64; i++) acc[i] = 0.f;

  for (int kb = k0; kb < k0 + kchunk; kb += 16) {
    __syncthreads();
    // stage A tile: 128 rows x 16 k  (512 float4)
    #pragma unroll
    for (int q = 0; q < 2; q++) {
      int idx = t + (q << 8);
      int row = idx >> 2;
      int c4  = (idx & 3) << 2;
      int gr  = m0 + row;
      int gk  = kb + c4;
      float4 v = make_float4(0.f, 0.f, 0.f, 0.f);
      if (gr < M) {
        const float* src;
        if (amode == 0) src = A + (size_t)gr * K + gk;
        else src = (gk < 2048) ? (A  + ((size_t)(gr >> 5) << 11) + gk)
                               : (A2 + ((size_t)gr << 11) + (gk - 2048));
        v = *(const float4*)src;
      }
      *(float4*)&As[row * 20 + c4] = v;
    }
    // stage B tile: 16 k x 128 cols, k-major padded layout
    #pragma unroll
    for (int q = 0; q < 2; q++) {
      int idx = t + (q << 8);
      int kk  = idx >> 5;
      int cq  = (idx & 31) << 2;
      float4 v = *(const float4*)(Bm + (size_t)(kb + kk) * N + n0 + cq);
      *(float4*)&Bs[bmap(kk, cq >> 2)] = v;
    }
    __syncthreads();
    #pragma unroll
    for (int kk4 = 0; kk4 < 16; kk4 += 4) {
      float4 a4[8];
      #pragma unroll
      for (int i = 0; i < 8; i++)
        a4[i] = *(const float4*)&As[(r0 + (i << 4)) * 20 + kk4];
      #pragma unroll
      for (int e = 0; e < 4; e++) {
        int kk = kk4 + e;
        float4 b0 = *(const float4*)&Bs[bmap(kk, (c0 >> 2))];
        float4 b1 = *(const float4*)&Bs[bmap(kk, (c0 >> 2) + 1)];
        float bv[8] = {b0.x, b0.y, b0.z, b0.w, b1.x, b1.y, b1.z, b1.w};
        #pragma unroll
        for (int i = 0; i < 8; i++) {
          float a = (e == 0) ? a4[i].x : (e == 1) ? a4[i].y : (e == 2) ? a4[i].z : a4[i].w;
          #pragma unroll
          for (int j = 0; j < 8; j++)
            acc[i * 8 + j] = fmaf(a, bv[j], acc[i * 8 + j]);
        }
      }
    }
  }
  float* Cz = Cpart + (size_t)blockIdx.z * M * N;
  #pragma unroll
  for (int i = 0; i < 8; i++) {
    int gr = m0 + r0 + (i << 4);
    if (gr < M) {
      float4 v0 = make_float4(acc[i * 8 + 0], acc[i * 8 + 1], acc[i * 8 + 2], acc[i * 8 + 3]);
      float4 v1 = make_float4(acc[i * 8 + 4], acc[i * 8 + 5], acc[i * 8 + 6], acc[i * 8 + 7]);
      *(float4*)&Cz[(size_t)gr * N + n0 + c0]     = v0;
      *(float4*)&Cz[(size_t)gr * N + n0 + c0 + 4] = v1;
    }
  }
}

// ---------------------------------------------------------------------------
// tproj = sum_z TPP[z]   (576x2048 floats, Z_TP planes)
// ---------------------------------------------------------------------------
__global__ __launch_bounds__(256) void reduce_tp(
    const float* __restrict__ tpp, float* __restrict__ tproj)
{
  int idx = blockIdx.x * 256 + threadIdx.x;     // float4 index, 294912 total
  const float4* p = (const float4*)tpp;
  float4 a = p[idx];
  #pragma unroll
  for (int z = 1; z < Z_TP; z++) {
    float4 b = p[idx + (size_t)z * 294912];
    a.x += b.x; a.y += b.y; a.z += b.z; a.w += b.w;
  }
  ((float4*)tproj)[idx] = a;
}

// ---------------------------------------------------------------------------
// Spart[z][b][x][col] = tproj[b,x,:] . att_d[b,col,:] over z's K-chunk.
// 64x128 tile (rows 36..63 wasted), 128 thr, 8x8 micro. Plain stores.
// ---------------------------------------------------------------------------
__global__ __launch_bounds__(128, 1) void sgemm36_part(
    const float* __restrict__ tproj, const float* __restrict__ attd,
    float* __restrict__ Spart, int kchunk)
{
  __shared__ float As[64 * 20];
  __shared__ float Bs[16 * 144];
  const int t  = threadIdx.x;
  const int n0 = blockIdx.x << 7;
  const int b  = blockIdx.y;
  const int k0 = blockIdx.z * kchunk;
  const int r0 = t >> 4;            // micro rows r0 + 8*i
  const int c0 = (t & 15) << 3;
  const float* Ab = tproj + (size_t)b * X_ * D_;
  const float* Bb = attd  + (size_t)b * NCOL * D_;
  float acc[64];
  #pragma unroll
  for (int i = 0; i < 64; i++) acc[i] = 0.f;

  for (int kb = k0; kb < k0 + kchunk; kb += 16) {
    __syncthreads();
    // stage A: 64 rows x 16 k (rows >= 36 zero)
    #pragma unroll
    for (int q = 0; q < 2; q++) {
      int idx = t + (q << 7);
      int row = idx >> 2;
      int c4  = (idx & 3) << 2;
      float4 v = make_float4(0.f, 0.f, 0.f, 0.f);
      if (row < X_) v = *(const float4*)(Ab + (size_t)row * D_ + kb + c4);
      *(float4*)&As[row * 20 + c4] = v;
    }
    // stage B^T: att_d rows are k-contiguous -> transpose on LDS store
    #pragma unroll
    for (int q = 0; q < 4; q++) {
      int idx = t + (q << 7);
      int col = idx >> 2;
      int kq  = (idx & 3) << 2;
      float4 v = *(const float4*)(Bb + (size_t)(n0 + col) * D_ + kb + kq);
      Bs[bmap(kq + 0, col >> 2) + (col & 3)] = v.x;
      Bs[bmap(kq + 1, col >> 2) + (col & 3)] = v.y;
      Bs[bmap(kq + 2, col >> 2) + (col & 3)] = v.z;
      Bs[bmap(kq + 3, col >> 2) + (col & 3)] = v.w;
    }
    __syncthreads();
    #pragma unroll
    for (int kk4 = 0; kk4 < 16; kk4 += 4) {
      float4 a4[8];
      #pragma unroll
      for (int i = 0; i < 8; i++)
        a4[i] = *(const float4*)&As[(r0 + (i << 3)) * 20 + kk4];
      #pragma unroll
      for (int e = 0; e < 4; e++) {
        int kk = kk4 + e;
        float4 b0 = *(const float4*)&Bs[bmap(kk, (c0 >> 2))];
        float4 b1 = *(const float4*)&Bs[bmap(kk, (c0 >> 2) + 1)];
        float bv[8] = {b0.x, b0.y, b0.z, b0.w, b1.x, b1.y, b1.z, b1.w};
        #pragma unroll
        for (int i = 0; i < 8; i++) {
          float a = (e == 0) ? a4[i].x : (e == 1) ? a4[i].y : (e == 2) ? a4[i].z : a4[i].w;
          #pragma unroll
          for (int j = 0; j < 8; j++)
            acc[i * 8 + j] = fmaf(a, bv[j], acc[i * 8 + j]);
        }
      }
    }
  }
  float* Sz = Spart + (size_t)blockIdx.z * SP_PLANE + (size_t)b * X_ * NCOL;
  #pragma unroll
  for (int i = 0; i < 8; i++) {
    int x = r0 + (i << 3);
    if (x < X_) {
      float4 v0 = make_float4(acc[i * 8 + 0], acc[i * 8 + 1], acc[i * 8 + 2], acc[i * 8 + 3]);
      float4 v1 = make_float4(acc[i * 8 + 4], acc[i * 8 + 5], acc[i * 8 + 6], acc[i * 8 + 7]);
      *(float4*)&Sz[(size_t)x * NCOL + n0 + c0]     = v0;
      *(float4*)&Sz[(size_t)x * NCOL + n0 + c0 + 4] = v1;
    }
  }
}

// ---------------------------------------------------------------------------
// scores[row] = relu(sum_z hp[z][row,:] + b1) . W2 + b2
// ---------------------------------------------------------------------------
__global__ __launch_bounds__(256) void mlp_tail_z(
    const float* __restrict__ hp, const float* __restrict__ b1,
    const float* __restrict__ w2, const float* __restrict__ b2,
    float* __restrict__ out)
{
  int row = blockIdx.x;
  int t   = threadIdx.x;
  float v = 0.f;
  #pragma unroll
  for (int q = 0; q < 2; q++) {
    int h = t + (q << 8);
    float s = 0.f;
    #pragma unroll
    for (int z = 0; z < Z_MLP; z++)
      s += hp[(size_t)z * (H_ * 512) + (size_t)row * H_ + h];
    s += b1[h];
    v += fmaxf(s, 0.f) * w2[h];
  }
  #pragma unroll
  for (int off = 32; off > 0; off >>= 1) v += __shfl_down(v, off, 64);
  __shared__ float red[4];
  if ((t & 63) == 0) red[t >> 6] = v;
  __syncthreads();
  if (t == 0) out[row] = red[0] + red[1] + red[2] + red[3] + b2[0];
}

// ---------------------------------------------------------------------------
// Per (b,i): sum z-planes of S, mask, row/col max, two softmaxes -> tw, dw
// ---------------------------------------------------------------------------
__global__ __launch_bounds__(64) void attn_weights(
    const float* __restrict__ Spart, const int* __restrict__ amt,
    const int* __restrict__ amd, float* __restrict__ tw, float* __restrict__ dw)
{
  __shared__ float Sm[36 * 37];
  __shared__ int   mtv[36], mdv[36];
  __shared__ float mrow[36], mcol[36];
  int bi = blockIdx.x;
  int b  = bi >> 5;
  int i  = bi & 31;
  int t  = threadIdx.x;
  if (t < 36) { mtv[t] = amt[b * 36 + t]; mdv[t] = amd[bi * 36 + t]; }
  __syncthreads();
  for (int idx = t; idx < 1296; idx += 64) {
    int x = idx / 36, y = idx - x * 36;
    size_t o = ((size_t)b * X_ + x) * NCOL + i * 36 + y;
    float v = Spart[o];
    #pragma unroll
    for (int z = 1; z < Z_S; z++) v += Spart[(size_t)z * SP_PLANE + o];
    Sm[x * 37 + y] = (mtv[x] != 0 && mdv[y] != 0) ? v : -1e9f;
  }
  __syncthreads();
  if (t < 36) {
    float r = -INFINITY, c = -INFINITY;
    for (int k = 0; k < 36; k++) {
      r = fmaxf(r, Sm[t * 37 + k]);
      c = fmaxf(c, Sm[k * 37 + t]);
    }
    mrow[t] = r; mcol[t] = c;
  }
  __syncthreads();
  {
    float v = (t < 36) ? mrow[t] : -INFINITY;
    float m = v;
    #pragma unroll
    for (int off = 32; off > 0; off >>= 1) m = fmaxf(m, __shfl_xor(m, off, 64));
    float e = (t < 36) ? expf(v - m) : 0.f;
    float s = e;
    #pragma unroll
    for (int off = 32; off > 0; off >>= 1) s += __shfl_xor(s, off, 64);
    if (t < 36) tw[bi * 36 + t] = e / s;
  }
  {
    float v = (t < 36) ? mcol[t] : -INFINITY;
    float m = v;
    #pragma unroll
    for (int off = 32; off > 0; off >>= 1) m = fmaxf(m, __shfl_xor(m, off, 64));
    float e = (t < 36) ? expf(v - m) : 0.f;
    float s = e;
    #pragma unroll
    for (int off = 32; off > 0; off >>= 1) s += __shfl_xor(s, off, 64);
    if (t < 36) dw[bi * 36 + t] = e / s;
  }
}

// ---------------------------------------------------------------------------
// cat_att[bi] = [ sum_x tw[x]*att_t[b,x,:], sum_y dw[y]*att_d[bi,y,:] ]
// ---------------------------------------------------------------------------
__global__ __launch_bounds__(256) void wfeats(
    const float* __restrict__ attt, const float* __restrict__ attd,
    const float* __restrict__ tw, const float* __restrict__ dw,
    float* __restrict__ cat)
{
  __shared__ float twl[36], dwl[36];
  int bi = blockIdx.x, b = bi >> 5, t = threadIdx.x;
  if (t < 36) { twl[t] = tw[bi * 36 + t]; dwl[t] = dw[bi * 36 + t]; }
  __syncthreads();
  const float4* at4 = (const float4*)(attt + (size_t)b * X_ * D_);
  const float4* ad4 = (const float4*)(attd + (size_t)bi * X_ * D_);
  float4 t0 = make_float4(0, 0, 0, 0), t1 = t0, d0 = t0, d1 = t0;
  for (int x = 0; x < 36; x++) {
    float wt = twl[x], wd = dwl[x];
    float4 a  = at4[x * 512 + t];
    float4 a2 = at4[x * 512 + t + 256];
    float4 e  = ad4[x * 512 + t];
    float4 e2 = ad4[x * 512 + t + 256];
    t0.x = fmaf(wt, a.x, t0.x);  t0.y = fmaf(wt, a.y, t0.y);
    t0.z = fmaf(wt, a.z, t0.z);  t0.w = fmaf(wt, a.w, t0.w);
    t1.x = fmaf(wt, a2.x, t1.x); t1.y = fmaf(wt, a2.y, t1.y);
    t1.z = fmaf(wt, a2.z, t1.z); t1.w = fmaf(wt, a2.w, t1.w);
    d0.x = fmaf(wd, e.x, d0.x);  d0.y = fmaf(wd, e.y, d0.y);
    d0.z = fmaf(wd, e.z, d0.z);  d0.w = fmaf(wd, e.w, d0.w);
    d1.x = fmaf(wd, e2.x, d1.x); d1.y = fmaf(wd, e2.y, d1.y);
    d1.z = fmaf(wd, e2.z, d1.z); d1.w = fmaf(wd, e2.w, d1.w);
  }
  float4* c4 = (float4*)(cat + (size_t)bi * K2D);
  c4[t] = t0; c4[t + 256] = t1; c4[512 + t] = d0; c4[512 + t + 256] = d1;
}

// ---------------------------------------------------------------------------
// out[b,:] = log_softmax(sb + so) over N=32
// ---------------------------------------------------------------------------
__global__ __launch_bounds__(64) void lsm(
    const float* __restrict__ sb, const float* __restrict__ so,
    float* __restrict__ out)
{
  int b = blockIdx.x, t = threadIdx.x;
  float s = (t < 32) ? sb[b * 32 + t] + so[b * 32 + t] : -INFINITY;
  float m = s;
  #pragma unroll
  for (int off = 32; off > 0; off >>= 1) m = fmaxf(m, __shfl_xor(m, off, 64));
  float e = (t < 32) ? expf(s - m) : 0.f;
  float sum = e;
  #pragma unroll
  for (int off = 32; off > 0; off >>= 1) sum += __shfl_xor(sum, off, 64);
  if (t < 32) out[b * 32 + t] = s - m - logf(sum);
}

extern "C" void kernel_launch(void* const* d_in, const int* in_sizes, int n_in,
                              void* d_out, int out_size, void* d_ws, size_t ws_size,
                              hipStream_t stream)
{
  const float* fc_t  = (const float*)d_in[0];
  const float* fc_d  = (const float*)d_in[1];
  const float* att_t = (const float*)d_in[2];
  const float* att_d = (const float*)d_in[3];
  const int*   am_t  = (const int*)d_in[4];
  const int*   am_d  = (const int*)d_in[5];
  const float* W1    = (const float*)d_in[6];
  const float* b1    = (const float*)d_in[7];
  const float* W2    = (const float*)d_in[8];
  const float* b2    = (const float*)d_in[9];
  const float* Wbil  = (const float*)d_in[10];
  const float* oW1   = (const float*)d_in[11];
  const float* ob1   = (const float*)d_in[12];
  const float* oW2   = (const float*)d_in[13];
  const float* ob2   = (const float*)d_in[14];
  float* ws  = (float*)d_ws;
  float* out = (float*)d_out;

  // 1. base scorer hidden partials: HP1[z] = concat(fc_t, fc_d) @ W1 (k-chunk z)
  gemm_part<<<dim3(4, 4, Z_MLP), 256, 0, stream>>>(fc_t, fc_d, W1, ws + O_A,
                                                   512, 512, 4096, 4096 / Z_MLP, 1);
  // 2. base scores (reduce z + bias + relu + dot W2)
  mlp_tail_z<<<512, 256, 0, stream>>>(ws + O_A, b1, W2, b2, ws + O_SB);
  // 3. tproj partials: TPP[z] = att_t @ Wbil  (A region free after step 2)
  gemm_part<<<dim3(16, 5, Z_TP), 256, 0, stream>>>(att_t, nullptr, Wbil, ws + O_A,
                                                   576, 2048, 2048, 2048 / Z_TP, 0);
  //    reduce -> TPROJ (B region)
  reduce_tp<<<1152, 256, 0, stream>>>(ws + O_A, ws + O_B);
  // 4. inners partials: SP[z] (A region free after reduce)
  sgemm36_part<<<dim3(9, 16, Z_S), 128, 0, stream>>>(ws + O_B, att_d, ws + O_A,
                                                     2048 / Z_S);
  // 5. attention weights (reduces SP z-planes on load)
  attn_weights<<<512, 64, 0, stream>>>(ws + O_A, am_t, am_d, ws + O_TW, ws + O_DW);
  // 6. weighted features -> CAT (B region; TPROJ dead)
  wfeats<<<512, 256, 0, stream>>>(att_t, att_d, ws + O_TW, ws + O_DW, ws + O_B);
  // 7. object scorer hidden partials: HP2[z] = CAT @ oW1 (A region free)
  gemm_part<<<dim3(4, 4, Z_MLP), 256, 0, stream>>>(ws + O_B, nullptr, oW1, ws + O_A,
                                                   512, 512, 4096, 4096 / Z_MLP, 0);
  // 8. object scores
  mlp_tail_z<<<512, 256, 0, stream>>>(ws + O_A, ob1, oW2, ob2, ws + O_SO);
  // 9. final log_softmax
  lsm<<<16, 64, 0, stream>>>(ws + O_SB, ws + O_SO, out);
}

// Round 3
// 509.404 us; speedup vs baseline: 2.0086x; 1.0685x over previous
//
#include <hip/hip_runtime.h>
#include <math.h>

// Problem constants
#define D_   2048
#define H_   512
#define K2D  4096
#define X_   36
#define NCOL 1152   // N * Y = 32*36

// Split-K factors (partials + fused reduce; NO atomics anywhere)
#define Z_MLP 16    // kchunk 256
#define Z_TP  4     // kchunk 512
#define Z_S   4     // kchunk 512

// ws layout (float offsets), regions reused sequentially (same as R2, 26.2 MB)
#define O_A   0u
#define O_B   4718592u
#define O_TW  6815744u
#define O_DW  6834176u
#define O_SB  6852608u
#define O_SO  6853120u

#define SP_PLANE 663552u   // 16*36*1152 per z-plane

// De-interleaved B-tile LDS layout: row stride 132 floats; chunk ch (of 32
// float4 chunks) stored at float offset (ch>>1)*4 + (ch&1)*64. Compute reads
// chunk 2l at dword 4l and chunk 2l+1 at dword 4l+64: 16 lanes x 64
// contiguous dwords each = 2/bank = conflict-free (m136). A tile: stride 20
// floats -> 4 distinct rows/wave-quarter span disjoint 4-bank groups.
#define BSTR 132

// ---------------------------------------------------------------------------
// fp32 GEMM, Cpart[z] = A@B over z's K-chunk. 128x128 tile, 256 thr, 8x8
// micro (rows strided 16). Register double-buffer: prefetch tile k+1 global
// loads during tile k compute. amode=1: A rows = concat(fc_t[row/32], fc_d[row]).
// ---------------------------------------------------------------------------
__global__ __launch_bounds__(256, 1) void gemm_part(
    const float* __restrict__ A, const float* __restrict__ A2,
    const float* __restrict__ Bm, float* __restrict__ Cpart,
    int M, int N, int K, int kchunk, int amode)
{
  __shared__ float As[128 * 20];
  __shared__ float Bs[16 * BSTR];
  const int t  = threadIdx.x;
  const int m0 = blockIdx.y << 7;
  const int n0 = blockIdx.x << 7;
  const int k0 = blockIdx.z * kchunk;
  const int kend = k0 + kchunk;
  const int r0 = t >> 4;             // micro rows r0 + 16*i
  const int c0 = (t & 15) << 3;      // micro cols c0 .. c0+7
  const int bl = (t & 15) << 2;      // B read dword offset (even chunk)

  // staging thread mapping
  const int sa_row = t >> 2;         // + 64 for q=1
  const int sa_c4  = (t & 3) << 2;
  const int sb_kk  = t >> 5;         // + 8 for q=1
  const int sb_ch  = t & 31;
  const int sb_slot = ((sb_ch >> 1) << 2) | ((sb_ch & 1) << 6);

  float acc[64];
  #pragma unroll
  for (int i = 0; i < 64; i++) acc[i] = 0.f;

  float4 ra[2], rb[2];

  auto loadA = [&](int kb) {
    #pragma unroll
    for (int q = 0; q < 2; q++) {
      int row = sa_row + (q << 6);
      int gr  = m0 + row;
      int gk  = kb + sa_c4;
      float4 v = make_float4(0.f, 0.f, 0.f, 0.f);
      if (gr < M) {
        const float* src;
        if (amode == 0) src = A + (size_t)gr * K + gk;
        else src = (gk < 2048) ? (A  + ((size_t)(gr >> 5) << 11) + gk)
                               : (A2 + ((size_t)gr << 11) + (gk - 2048));
        v = *(const float4*)src;
      }
      ra[q] = v;
    }
  };
  auto loadB = [&](int kb) {
    #pragma unroll
    for (int q = 0; q < 2; q++)
      rb[q] = *(const float4*)(Bm + (size_t)(kb + sb_kk + (q << 3)) * N
                               + n0 + (sb_ch << 2));
  };

  loadA(k0); loadB(k0);

  for (int kb = k0; kb < kend; kb += 16) {
    __syncthreads();
    #pragma unroll
    for (int q = 0; q < 2; q++)
      *(float4*)&As[(sa_row + (q << 6)) * 20 + sa_c4] = ra[q];
    #pragma unroll
    for (int q = 0; q < 2; q++)
      *(float4*)&Bs[(sb_kk + (q << 3)) * BSTR + sb_slot] = rb[q];
    __syncthreads();
    if (kb + 16 < kend) { loadA(kb + 16); loadB(kb + 16); }
    #pragma unroll
    for (int kk4 = 0; kk4 < 16; kk4 += 4) {
      float4 a4[8];
      #pragma unroll
      for (int i = 0; i < 8; i++)
        a4[i] = *(const float4*)&As[(r0 + (i << 4)) * 20 + kk4];
      #pragma unroll
      for (int e = 0; e < 4; e++) {
        int kk = kk4 + e;
        float4 b0 = *(const float4*)&Bs[kk * BSTR + bl];
        float4 b1 = *(const float4*)&Bs[kk * BSTR + bl + 64];
        float bv[8] = {b0.x, b0.y, b0.z, b0.w, b1.x, b1.y, b1.z, b1.w};
        #pragma unroll
        for (int i = 0; i < 8; i++) {
          float a = (e == 0) ? a4[i].x : (e == 1) ? a4[i].y : (e == 2) ? a4[i].z : a4[i].w;
          #pragma unroll
          for (int j = 0; j < 8; j++)
            acc[i * 8 + j] = fmaf(a, bv[j], acc[i * 8 + j]);
        }
      }
    }
  }
  float* Cz = Cpart + (size_t)blockIdx.z * M * N;
  #pragma unroll
  for (int i = 0; i < 8; i++) {
    int gr = m0 + r0 + (i << 4);
    if (gr < M) {
      float4 v0 = make_float4(acc[i * 8 + 0], acc[i * 8 + 1], acc[i * 8 + 2], acc[i * 8 + 3]);
      float4 v1 = make_float4(acc[i * 8 + 4], acc[i * 8 + 5], acc[i * 8 + 6], acc[i * 8 + 7]);
      *(float4*)&Cz[(size_t)gr * N + n0 + c0]     = v0;
      *(float4*)&Cz[(size_t)gr * N + n0 + c0 + 4] = v1;
    }
  }
}

// ---------------------------------------------------------------------------
// tproj = sum_z TPP[z]   (576x2048 floats, Z_TP planes)
// ---------------------------------------------------------------------------
__global__ __launch_bounds__(256) void reduce_tp(
    const float* __restrict__ tpp, float* __restrict__ tproj)
{
  int idx = blockIdx.x * 256 + threadIdx.x;     // float4 index, 294912 total
  const float4* p = (const float4*)tpp;
  float4 a = p[idx];
  #pragma unroll
  for (int z = 1; z < Z_TP; z++) {
    float4 b = p[idx + (size_t)z * 294912];
    a.x += b.x; a.y += b.y; a.z += b.z; a.w += b.w;
  }
  ((float4*)tproj)[idx] = a;
}

// ---------------------------------------------------------------------------
// Spart[z][b][x][col] = tproj[b,x,:] . att_d[b,col,:] over z's K-chunk.
// 64x128 tile (rows 36..63 zero), 128 thr, 8x8 micro, register dbuf.
// ---------------------------------------------------------------------------
__global__ __launch_bounds__(128, 1) void sgemm36_part(
    const float* __restrict__ tproj, const float* __restrict__ attd,
    float* __restrict__ Spart, int kchunk)
{
  __shared__ float As[64 * 20];
  __shared__ float Bs[16 * BSTR];
  const int t  = threadIdx.x;
  const int n0 = blockIdx.x << 7;
  const int b  = blockIdx.y;
  const int k0 = blockIdx.z * kchunk;
  const int kend = k0 + kchunk;
  const int r0 = t >> 4;            // micro rows r0 + 8*i
  const int c0 = (t & 15) << 3;
  const int bl = (t & 15) << 2;
  const float* Ab = tproj + (size_t)b * X_ * D_;
  const float* Bb = attd  + (size_t)b * NCOL * D_;

  // staging maps
  const int sa_row = t >> 2;        // + 32 for q=1
  const int sa_c4  = (t & 3) << 2;
  const int bcol0  = t & 31;        // + 32q
  const int bkq    = (t >> 5) << 2; // k offset 0/4/8/12

  float acc[64];
  #pragma unroll
  for (int i = 0; i < 64; i++) acc[i] = 0.f;

  float4 ra[2], rbt[4];

  auto loadA = [&](int kb) {
    #pragma unroll
    for (int q = 0; q < 2; q++) {
      int row = sa_row + (q << 5);
      float4 v = make_float4(0.f, 0.f, 0.f, 0.f);
      if (row < X_) v = *(const float4*)(Ab + (size_t)row * D_ + kb + sa_c4);
      ra[q] = v;
    }
  };
  auto loadBT = [&](int kb) {
    #pragma unroll
    for (int q = 0; q < 4; q++) {
      int col = bcol0 + (q << 5);
      rbt[q] = *(const float4*)(Bb + (size_t)(n0 + col) * D_ + kb + bkq);
    }
  };

  loadA(k0); loadBT(k0);

  for (int kb = k0; kb < kend; kb += 16) {
    __syncthreads();
    #pragma unroll
    for (int q = 0; q < 2; q++)
      *(float4*)&As[(sa_row + (q << 5)) * 20 + sa_c4] = ra[q];
    #pragma unroll
    for (int q = 0; q < 4; q++) {
      int col  = bcol0 + (q << 5);
      int ch   = col >> 2;
      int slot = (((ch >> 1) << 2) | ((ch & 1) << 6)) + (col & 3);
      Bs[(bkq + 0) * BSTR + slot] = rbt[q].x;
      Bs[(bkq + 1) * BSTR + slot] = rbt[q].y;
      Bs[(bkq + 2) * BSTR + slot] = rbt[q].z;
      Bs[(bkq + 3) * BSTR + slot] = rbt[q].w;
    }
    __syncthreads();
    if (kb + 16 < kend) { loadA(kb + 16); loadBT(kb + 16); }
    #pragma unroll
    for (int kk4 = 0; kk4 < 16; kk4 += 4) {
      float4 a4[8];
      #pragma unroll
      for (int i = 0; i < 8; i++)
        a4[i] = *(const float4*)&As[(r0 + (i << 3)) * 20 + kk4];
      #pragma unroll
      for (int e = 0; e < 4; e++) {
        int kk = kk4 + e;
        float4 b0 = *(const float4*)&Bs[kk * BSTR + bl];
        float4 b1 = *(const float4*)&Bs[kk * BSTR + bl + 64];
        float bv[8] = {b0.x, b0.y, b0.z, b0.w, b1.x, b1.y, b1.z, b1.w};
        #pragma unroll
        for (int i = 0; i < 8; i++) {
          float a = (e == 0) ? a4[i].x : (e == 1) ? a4[i].y : (e == 2) ? a4[i].z : a4[i].w;
          #pragma unroll
          for (int j = 0; j < 8; j++)
            acc[i * 8 + j] = fmaf(a, bv[j], acc[i * 8 + j]);
        }
      }
    }
  }
  float* Sz = Spart + (size_t)blockIdx.z * SP_PLANE + (size_t)b * X_ * NCOL;
  #pragma unroll
  for (int i = 0; i < 8; i++) {
    int x = r0 + (i << 3);
    if (x < X_) {
      float4 v0 = make_float4(acc[i * 8 + 0], acc[i * 8 + 1], acc[i * 8 + 2], acc[i * 8 + 3]);
      float4 v1 = make_float4(acc[i * 8 + 4], acc[i * 8 + 5], acc[i * 8 + 6], acc[i * 8 + 7]);
      *(float4*)&Sz[(size_t)x * NCOL + n0 + c0]     = v0;
      *(float4*)&Sz[(size_t)x * NCOL + n0 + c0 + 4] = v1;
    }
  }
}

// ---------------------------------------------------------------------------
// scores[row] = relu(sum_z hp[z][row,:] + b1) . W2 + b2
// ---------------------------------------------------------------------------
__global__ __launch_bounds__(256) void mlp_tail_z(
    const float* __restrict__ hp, const float* __restrict__ b1,
    const float* __restrict__ w2, const float* __restrict__ b2,
    float* __restrict__ out)
{
  int row = blockIdx.x;
  int t   = threadIdx.x;
  float v = 0.f;
  #pragma unroll
  for (int q = 0; q < 2; q++) {
    int h = t + (q << 8);
    float s = 0.f;
    #pragma unroll
    for (int z = 0; z < Z_MLP; z++)
      s += hp[(size_t)z * (H_ * 512) + (size_t)row * H_ + h];
    s += b1[h];
    v += fmaxf(s, 0.f) * w2[h];
  }
  #pragma unroll
  for (int off = 32; off > 0; off >>= 1) v += __shfl_down(v, off, 64);
  __shared__ float red[4];
  if ((t & 63) == 0) red[t >> 6] = v;
  __syncthreads();
  if (t == 0) out[row] = red[0] + red[1] + red[2] + red[3] + b2[0];
}

// ---------------------------------------------------------------------------
// Per (b,i): sum z-planes of S, mask, row/col max, two softmaxes -> tw, dw
// ---------------------------------------------------------------------------
__global__ __launch_bounds__(64) void attn_weights(
    const float* __restrict__ Spart, const int* __restrict__ amt,
    const int* __restrict__ amd, float* __restrict__ tw, float* __restrict__ dw)
{
  __shared__ float Sm[36 * 37];
  __shared__ int   mtv[36], mdv[36];
  __shared__ float mrow[36], mcol[36];
  int bi = blockIdx.x;
  int b  = bi >> 5;
  int i  = bi & 31;
  int t  = threadIdx.x;
  if (t < 36) { mtv[t] = amt[b * 36 + t]; mdv[t] = amd[bi * 36 + t]; }
  __syncthreads();
  // 36 rows x 9 float4 per z-plane
  for (int f = t; f < 324; f += 64) {
    int x  = f / 9;
    int yq = (f - x * 9) << 2;
    size_t o = (((size_t)b * X_ + x) * NCOL + i * 36 + yq) >> 2;
    const float4* p = (const float4*)Spart;
    float4 v = p[o];
    #pragma unroll
    for (int z = 1; z < Z_S; z++) {
      float4 w = p[o + ((size_t)z * SP_PLANE >> 2)];
      v.x += w.x; v.y += w.y; v.z += w.z; v.w += w.w;
    }
    float* dst = &Sm[x * 37 + yq];
    bool mx = (mtv[x] != 0);
    dst[0] = (mx && mdv[yq + 0] != 0) ? v.x : -1e9f;
    dst[1] = (mx && mdv[yq + 1] != 0) ? v.y : -1e9f;
    dst[2] = (mx && mdv[yq + 2] != 0) ? v.z : -1e9f;
    dst[3] = (mx && mdv[yq + 3] != 0) ? v.w : -1e9f;
  }
  __syncthreads();
  if (t < 36) {
    float r = -INFINITY, c = -INFINITY;
    for (int k = 0; k < 36; k++) {
      r = fmaxf(r, Sm[t * 37 + k]);
      c = fmaxf(c, Sm[k * 37 + t]);
    }
    mrow[t] = r; mcol[t] = c;
  }
  __syncthreads();
  {
    float v = (t < 36) ? mrow[t] : -INFINITY;
    float m = v;
    #pragma unroll
    for (int off = 32; off > 0; off >>= 1) m = fmaxf(m, __shfl_xor(m, off, 64));
    float e = (t < 36) ? expf(v - m) : 0.f;
    float s = e;
    #pragma unroll
    for (int off = 32; off > 0; off >>= 1) s += __shfl_xor(s, off, 64);
    if (t < 36) tw[bi * 36 + t] = e / s;
  }
  {
    float v = (t < 36) ? mcol[t] : -INFINITY;
    float m = v;
    #pragma unroll
    for (int off = 32; off > 0; off >>= 1) m = fmaxf(m, __shfl_xor(m, off, 64));
    float e = (t < 36) ? expf(v - m) : 0.f;
    float s = e;
    #pragma unroll
    for (int off = 32; off > 0; off >>= 1) s += __shfl_xor(s, off, 64);
    if (t < 36) dw[bi * 36 + t] = e / s;
  }
}

// ---------------------------------------------------------------------------
// cat_att[bi] = [ sum_x tw[x]*att_t[b,x,:], sum_y dw[y]*att_d[bi,y,:] ]
// ---------------------------------------------------------------------------
__global__ __launch_bounds__(256) void wfeats(
    const float* __restrict__ attt, const float* __restrict__ attd,
    const float* __restrict__ tw, const float* __restrict__ dw,
    float* __restrict__ cat)
{
  __shared__ float twl[36], dwl[36];
  int bi = blockIdx.x, b = bi >> 5, t = threadIdx.x;
  if (t < 36) { twl[t] = tw[bi * 36 + t]; dwl[t] = dw[bi * 36 + t]; }
  __syncthreads();
  const float4* at4 = (const float4*)(attt + (size_t)b * X_ * D_);
  const float4* ad4 = (const float4*)(attd + (size_t)bi * X_ * D_);
  float4 t0 = make_float4(0, 0, 0, 0), t1 = t0, d0 = t0, d1 = t0;
  for (int x = 0; x < 36; x++) {
    float wt = twl[x], wd = dwl[x];
    float4 a  = at4[x * 512 + t];
    float4 a2 = at4[x * 512 + t + 256];
    float4 e  = ad4[x * 512 + t];
    float4 e2 = ad4[x * 512 + t + 256];
    t0.x = fmaf(wt, a.x, t0.x);  t0.y = fmaf(wt, a.y, t0.y);
    t0.z = fmaf(wt, a.z, t0.z);  t0.w = fmaf(wt, a.w, t0.w);
    t1.x = fmaf(wt, a2.x, t1.x); t1.y = fmaf(wt, a2.y, t1.y);
    t1.z = fmaf(wt, a2.z, t1.z); t1.w = fmaf(wt, a2.w, t1.w);
    d0.x = fmaf(wd, e.x, d0.x);  d0.y = fmaf(wd, e.y, d0.y);
    d0.z = fmaf(wd, e.z, d0.z);  d0.w = fmaf(wd, e.w, d0.w);
    d1.x = fmaf(wd, e2.x, d1.x); d1.y = fmaf(wd, e2.y, d1.y);
    d1.z = fmaf(wd, e2.z, d1.z); d1.w = fmaf(wd, e2.w, d1.w);
  }
  float4* c4 = (float4*)(cat + (size_t)bi * K2D);
  c4[t] = t0; c4[t + 256] = t1; c4[512 + t] = d0; c4[512 + t + 256] = d1;
}

// ---------------------------------------------------------------------------
// out[b,:] = log_softmax(sb + so) over N=32
// ---------------------------------------------------------------------------
__global__ __launch_bounds__(64) void lsm(
    const float* __restrict__ sb, const float* __restrict__ so,
    float* __restrict__ out)
{
  int b = blockIdx.x, t = threadIdx.x;
  float s = (t < 32) ? sb[b * 32 + t] + so[b * 32 + t] : -INFINITY;
  float m = s;
  #pragma unroll
  for (int off = 32; off > 0; off >>= 1) m = fmaxf(m, __shfl_xor(m, off, 64));
  float e = (t < 32) ? expf(s - m) : 0.f;
  float sum = e;
  #pragma unroll
  for (int off = 32; off > 0; off >>= 1) sum += __shfl_xor(sum, off, 64);
  if (t < 32) out[b * 32 + t] = s - m - logf(sum);
}

extern "C" void kernel_launch(void* const* d_in, const int* in_sizes, int n_in,
                              void* d_out, int out_size, void* d_ws, size_t ws_size,
                              hipStream_t stream)
{
  const float* fc_t  = (const float*)d_in[0];
  const float* fc_d  = (const float*)d_in[1];
  const float* att_t = (const float*)d_in[2];
  const float* att_d = (const float*)d_in[3];
  const int*   am_t  = (const int*)d_in[4];
  const int*   am_d  = (const int*)d_in[5];
  const float* W1    = (const float*)d_in[6];
  const float* b1    = (const float*)d_in[7];
  const float* W2    = (const float*)d_in[8];
  const float* b2    = (const float*)d_in[9];
  const float* Wbil  = (const float*)d_in[10];
  const float* oW1   = (const float*)d_in[11];
  const float* ob1   = (const float*)d_in[12];
  const float* oW2   = (const float*)d_in[13];
  const float* ob2   = (const float*)d_in[14];
  float* ws  = (float*)d_ws;
  float* out = (float*)d_out;

  // 1. base scorer hidden partials: HP1[z] = concat(fc_t, fc_d) @ W1
  gemm_part<<<dim3(4, 4, Z_MLP), 256, 0, stream>>>(fc_t, fc_d, W1, ws + O_A,
                                                   512, 512, 4096, 4096 / Z_MLP, 1);
  // 2. base scores
  mlp_tail_z<<<512, 256, 0, stream>>>(ws + O_A, b1, W2, b2, ws + O_SB);
  // 3. tproj partials: TPP[z] = att_t @ Wbil
  gemm_part<<<dim3(16, 5, Z_TP), 256, 0, stream>>>(att_t, nullptr, Wbil, ws + O_A,
                                                   576, 2048, 2048, 2048 / Z_TP, 0);
  reduce_tp<<<1152, 256, 0, stream>>>(ws + O_A, ws + O_B);
  // 4. inners partials
  sgemm36_part<<<dim3(9, 16, Z_S), 128, 0, stream>>>(ws + O_B, att_d, ws + O_A,
                                                     2048 / Z_S);
  // 5. attention weights
  attn_weights<<<512, 64, 0, stream>>>(ws + O_A, am_t, am_d, ws + O_TW, ws + O_DW);
  // 6. weighted features -> CAT
  wfeats<<<512, 256, 0, stream>>>(att_t, att_d, ws + O_TW, ws + O_DW, ws + O_B);
  // 7. object scorer hidden partials: HP2[z] = CAT @ oW1
  gemm_part<<<dim3(4, 4, Z_MLP), 256, 0, stream>>>(ws + O_B, nullptr, oW1, ws + O_A,
                                                   512, 512, 4096, 4096 / Z_MLP, 0);
  // 8. object scores
  mlp_tail_z<<<512, 256, 0, stream>>>(ws + O_A, ob1, oW2, ob2, ws + O_SO);
  // 9. final log_softmax
  lsm<<<16, 64, 0, stream>>>(ws + O_SB, ws + O_SO, out);
}

// Round 4
// 416.486 us; speedup vs baseline: 2.4568x; 1.2231x over previous
//
#include <hip/hip_runtime.h>
#include <math.h>

// Problem constants
#define D_   2048
#define H_   512
#define K2D  4096
#define X_   36
#define NCOL 1152   // N * Y = 32*36

// Split-K factors (partials + fused reduce; NO atomics anywhere)
#define Z_MLP 16    // kchunk 256
#define Z_TP  4     // kchunk 512
#define Z_S   2     // kchunk 1024

// ws layout (float offsets), regions reused sequentially (26.2 MB, same as R3)
//  A: HP1 (16x262144) -> TPP (4x1179648) -> SP (2x663552) -> HP2
//  B: TPROJ (1179648) -> CAT (2097152)
#define O_A   0u
#define O_B   4718592u
#define O_TW  6815744u
#define O_DW  6834176u
#define O_SB  6852608u
#define O_SO  6853120u

#define SP_PLANE 663552u   // 16*36*1152 per z-plane

typedef __attribute__((ext_vector_type(8))) short bf8_t;   // 8 bf16 (4 VGPRs)
typedef __attribute__((ext_vector_type(4))) float f4_t;    // MFMA accumulator

// fp32 -> bf16 round-to-nearest-even, and back
__device__ __forceinline__ unsigned short f2bf(float f) {
  unsigned u = __float_as_uint(f);
  unsigned r = u + 0x7FFFu + ((u >> 16) & 1u);
  return (unsigned short)(r >> 16);
}
__device__ __forceinline__ float bf2f(unsigned short h) {
  return __uint_as_float(((unsigned)h) << 16);
}

// LDS tile row stride: 40 ushorts = 80 B (16B-aligned rows, uniform bank spread)
#define TSTR 40

// ---------------------------------------------------------------------------
// Split-bf16 MFMA GEMM: Cpart[z] = A@B over z's K-chunk (fp32 in, fp32 out).
// x*y ~= hi_x*hi_y + hi_x*lo_y + lo_x*hi_y  (3 MFMAs, lo*lo ~2^-16 dropped).
// Tile 128x128, 256 thr / 4 waves, wave tile 64x64 (4x4 frags of 16x16x32).
// Staging: threads 0-127 transpose+split B cols; 128-255 split A rows.
// amode=1: A rows = concat(fc_t[row/32], fc_d[row]).
// ---------------------------------------------------------------------------
__global__ __launch_bounds__(256, 1) void gemm_mfma(
    const float* __restrict__ A, const float* __restrict__ A2,
    const float* __restrict__ Bm, float* __restrict__ Cpart,
    int M, int N, int K, int kchunk, int amode)
{
  __shared__ __align__(16) unsigned short AsH[128 * TSTR], AsL[128 * TSTR];
  __shared__ __align__(16) unsigned short BsH[128 * TSTR], BsL[128 * TSTR];
  const int t  = threadIdx.x;
  const int m0 = blockIdx.y << 7;
  const int n0 = blockIdx.x << 7;
  const int k0 = blockIdx.z * kchunk;
  const int kend = k0 + kchunk;
  const int w  = t >> 6;          // wave 0..3
  const int ln = t & 15;          // lane&15
  const int qd = (t >> 4) & 3;    // quad
  const int wm = (w >> 1) << 6;   // wave m offset 0/64
  const int wn = (w & 1) << 6;    // wave n offset 0/64

  f4_t acc[4][4];
  #pragma unroll
  for (int i = 0; i < 4; i++)
    #pragma unroll
    for (int j = 0; j < 4; j++) acc[i][j] = (f4_t)0.f;

  for (int kb = k0; kb < kend; kb += 32) {
    __syncthreads();
    if (t < 128) {
      // B column loader: gather 32 k for col t, split, write k-contiguous
      int col = t;
      float v[32];
      #pragma unroll
      for (int k = 0; k < 32; k++)
        v[k] = Bm[(size_t)(kb + k) * N + n0 + col];
      __align__(16) unsigned short hb[32], lb[32];
      #pragma unroll
      for (int k = 0; k < 32; k++) {
        unsigned short h = f2bf(v[k]);
        hb[k] = h;
        lb[k] = f2bf(v[k] - bf2f(h));
      }
      #pragma unroll
      for (int j = 0; j < 4; j++) {
        *(bf8_t*)&BsH[col * TSTR + j * 8] = *(bf8_t*)&hb[j * 8];
        *(bf8_t*)&BsL[col * TSTR + j * 8] = *(bf8_t*)&lb[j * 8];
      }
    } else {
      // A row loader
      int row = t - 128;
      int gr  = m0 + row;
      float4 va[8];
      #pragma unroll
      for (int j = 0; j < 8; j++) va[j] = make_float4(0.f, 0.f, 0.f, 0.f);
      if (gr < M) {
        #pragma unroll
        for (int j = 0; j < 8; j++) {
          int gk = kb + (j << 2);
          const float* src;
          if (amode == 0) src = A + (size_t)gr * K + gk;
          else src = (gk < 2048) ? (A  + ((size_t)(gr >> 5) << 11) + gk)
                                 : (A2 + ((size_t)gr << 11) + (gk - 2048));
          va[j] = *(const float4*)src;
        }
      }
      __align__(16) unsigned short hb[32], lb[32];
      #pragma unroll
      for (int j = 0; j < 8; j++) {
        float x0 = va[j].x, x1 = va[j].y, x2 = va[j].z, x3 = va[j].w;
        unsigned short h0 = f2bf(x0), h1 = f2bf(x1), h2 = f2bf(x2), h3 = f2bf(x3);
        hb[4*j+0] = h0; hb[4*j+1] = h1; hb[4*j+2] = h2; hb[4*j+3] = h3;
        lb[4*j+0] = f2bf(x0 - bf2f(h0));
        lb[4*j+1] = f2bf(x1 - bf2f(h1));
        lb[4*j+2] = f2bf(x2 - bf2f(h2));
        lb[4*j+3] = f2bf(x3 - bf2f(h3));
      }
      #pragma unroll
      for (int j = 0; j < 4; j++) {
        *(bf8_t*)&AsH[row * TSTR + j * 8] = *(bf8_t*)&hb[j * 8];
        *(bf8_t*)&AsL[row * TSTR + j * 8] = *(bf8_t*)&lb[j * 8];
      }
    }
    __syncthreads();
    // fragments: lane holds 8 consecutive k at k = qd*8..qd*8+7
    bf8_t ah[4], al[4], bh[4], bl[4];
    #pragma unroll
    for (int fm = 0; fm < 4; fm++) {
      int r = (wm + (fm << 4) + ln) * TSTR + (qd << 3);
      ah[fm] = *(const bf8_t*)&AsH[r];
      al[fm] = *(const bf8_t*)&AsL[r];
    }
    #pragma unroll
    for (int fn = 0; fn < 4; fn++) {
      int r = (wn + (fn << 4) + ln) * TSTR + (qd << 3);
      bh[fn] = *(const bf8_t*)&BsH[r];
      bl[fn] = *(const bf8_t*)&BsL[r];
    }
    #pragma unroll
    for (int fm = 0; fm < 4; fm++)
      #pragma unroll
      for (int fn = 0; fn < 4; fn++) {
        acc[fm][fn] = __builtin_amdgcn_mfma_f32_16x16x32_bf16(ah[fm], bh[fn], acc[fm][fn], 0, 0, 0);
        acc[fm][fn] = __builtin_amdgcn_mfma_f32_16x16x32_bf16(ah[fm], bl[fn], acc[fm][fn], 0, 0, 0);
        acc[fm][fn] = __builtin_amdgcn_mfma_f32_16x16x32_bf16(al[fm], bh[fn], acc[fm][fn], 0, 0, 0);
      }
  }
  // epilogue: C/D layout row = qd*4+reg, col = ln  [m89-verified]
  float* Cz = Cpart + (size_t)blockIdx.z * M * N;
  #pragma unroll
  for (int fm = 0; fm < 4; fm++) {
    #pragma unroll
    for (int reg = 0; reg < 4; reg++) {
      int gr = m0 + wm + (fm << 4) + (qd << 2) + reg;
      if (gr < M) {
        #pragma unroll
        for (int fn = 0; fn < 4; fn++)
          Cz[(size_t)gr * N + n0 + wn + (fn << 4) + ln] = acc[fm][fn][reg];
      }
    }
  }
}

// ---------------------------------------------------------------------------
// tproj = sum_z TPP[z]   (576x2048 floats, Z_TP planes)
// ---------------------------------------------------------------------------
__global__ __launch_bounds__(256) void reduce_tp(
    const float* __restrict__ tpp, float* __restrict__ tproj)
{
  int idx = blockIdx.x * 256 + threadIdx.x;     // float4 index, 294912 total
  const float4* p = (const float4*)tpp;
  float4 a = p[idx];
  #pragma unroll
  for (int z = 1; z < Z_TP; z++) {
    float4 b = p[idx + (size_t)z * 294912];
    a.x += b.x; a.y += b.y; a.z += b.z; a.w += b.w;
  }
  ((float4*)tproj)[idx] = a;
}

// ---------------------------------------------------------------------------
// Spart[z][b][x][col] = tproj[b,x,:] . att_d[b,col,:] over z's K-chunk.
// MFMA split-bf16. Tile M=48 (x rows, >=36 zero) x N=128 cols, 256 thr.
// Wave w: cols w*32..w*32+31 (2 n-frags) x 3 m-frags.
// ---------------------------------------------------------------------------
__global__ __launch_bounds__(256, 1) void sgemm36_mfma(
    const float* __restrict__ tproj, const float* __restrict__ attd,
    float* __restrict__ Spart, int kchunk)
{
  __shared__ __align__(16) unsigned short AsH[48 * TSTR], AsL[48 * TSTR];
  __shared__ __align__(16) unsigned short BsH[128 * TSTR], BsL[128 * TSTR];
  const int t  = threadIdx.x;
  const int n0 = blockIdx.x << 7;
  const int b  = blockIdx.y;
  const int k0 = blockIdx.z * kchunk;
  const int kend = k0 + kchunk;
  const int w  = t >> 6;
  const int ln = t & 15;
  const int qd = (t >> 4) & 3;
  const float* Ab = tproj + (size_t)b * X_ * D_;
  const float* Bb = attd  + (size_t)b * NCOL * D_;

  f4_t acc[3][2];
  #pragma unroll
  for (int i = 0; i < 3; i++)
    #pragma unroll
    for (int j = 0; j < 2; j++) acc[i][j] = (f4_t)0.f;

  for (int kb = k0; kb < kend; kb += 32) {
    __syncthreads();
    if (t < 128) {
      // B loader: att_d rows are k-contiguous already
      int col = t;
      float4 v[8];
      #pragma unroll
      for (int j = 0; j < 8; j++)
        v[j] = *(const float4*)(Bb + (size_t)(n0 + col) * D_ + kb + (j << 2));
      __align__(16) unsigned short hb[32], lb[32];
      #pragma unroll
      for (int j = 0; j < 8; j++) {
        float x0 = v[j].x, x1 = v[j].y, x2 = v[j].z, x3 = v[j].w;
        unsigned short h0 = f2bf(x0), h1 = f2bf(x1), h2 = f2bf(x2), h3 = f2bf(x3);
        hb[4*j+0] = h0; hb[4*j+1] = h1; hb[4*j+2] = h2; hb[4*j+3] = h3;
        lb[4*j+0] = f2bf(x0 - bf2f(h0));
        lb[4*j+1] = f2bf(x1 - bf2f(h1));
        lb[4*j+2] = f2bf(x2 - bf2f(h2));
        lb[4*j+3] = f2bf(x3 - bf2f(h3));
      }
      #pragma unroll
      for (int j = 0; j < 4; j++) {
        *(bf8_t*)&BsH[col * TSTR + j * 8] = *(bf8_t*)&hb[j * 8];
        *(bf8_t*)&BsL[col * TSTR + j * 8] = *(bf8_t*)&lb[j * 8];
      }
    } else if (t < 176) {
      // A loader: 48 rows (36 real, 12 zero-pad)
      int row = t - 128;
      float4 v[8];
      #pragma unroll
      for (int j = 0; j < 8; j++) v[j] = make_float4(0.f, 0.f, 0.f, 0.f);
      if (row < X_) {
        #pragma unroll
        for (int j = 0; j < 8; j++)
          v[j] = *(const float4*)(Ab + (size_t)row * D_ + kb + (j << 2));
      }
      __align__(16) unsigned short hb[32], lb[32];
      #pragma unroll
      for (int j = 0; j < 8; j++) {
        float x0 = v[j].x, x1 = v[j].y, x2 = v[j].z, x3 = v[j].w;
        unsigned short h0 = f2bf(x0), h1 = f2bf(x1), h2 = f2bf(x2), h3 = f2bf(x3);
        hb[4*j+0] = h0; hb[4*j+1] = h1; hb[4*j+2] = h2; hb[4*j+3] = h3;
        lb[4*j+0] = f2bf(x0 - bf2f(h0));
        lb[4*j+1] = f2bf(x1 - bf2f(h1));
        lb[4*j+2] = f2bf(x2 - bf2f(h2));
        lb[4*j+3] = f2bf(x3 - bf2f(h3));
      }
      #pragma unroll
      for (int j = 0; j < 4; j++) {
        *(bf8_t*)&AsH[row * TSTR + j * 8] = *(bf8_t*)&hb[j * 8];
        *(bf8_t*)&AsL[row * TSTR + j * 8] = *(bf8_t*)&lb[j * 8];
      }
    }
    __syncthreads();
    bf8_t ah[3], al[3], bh[2], bl[2];
    #pragma unroll
    for (int fm = 0; fm < 3; fm++) {
      int r = ((fm << 4) + ln) * TSTR + (qd << 3);
      ah[fm] = *(const bf8_t*)&AsH[r];
      al[fm] = *(const bf8_t*)&AsL[r];
    }
    #pragma unroll
    for (int fn = 0; fn < 2; fn++) {
      int r = ((w << 5) + (fn << 4) + ln) * TSTR + (qd << 3);
      bh[fn] = *(const bf8_t*)&BsH[r];
      bl[fn] = *(const bf8_t*)&BsL[r];
    }
    #pragma unroll
    for (int fm = 0; fm < 3; fm++)
      #pragma unroll
      for (int fn = 0; fn < 2; fn++) {
        acc[fm][fn] = __builtin_amdgcn_mfma_f32_16x16x32_bf16(ah[fm], bh[fn], acc[fm][fn], 0, 0, 0);
        acc[fm][fn] = __builtin_amdgcn_mfma_f32_16x16x32_bf16(ah[fm], bl[fn], acc[fm][fn], 0, 0, 0);
        acc[fm][fn] = __builtin_amdgcn_mfma_f32_16x16x32_bf16(al[fm], bh[fn], acc[fm][fn], 0, 0, 0);
      }
  }
  float* Sz = Spart + (size_t)blockIdx.z * SP_PLANE + (size_t)b * X_ * NCOL;
  #pragma unroll
  for (int fm = 0; fm < 3; fm++) {
    #pragma unroll
    for (int reg = 0; reg < 4; reg++) {
      int x = (fm << 4) + (qd << 2) + reg;
      if (x < X_) {
        #pragma unroll
        for (int fn = 0; fn < 2; fn++) {
          int col = n0 + (w << 5) + (fn << 4) + ln;
          Sz[(size_t)x * NCOL + col] = acc[fm][fn][reg];
        }
      }
    }
  }
}

// ---------------------------------------------------------------------------
// scores[row] = relu(sum_z hp[z][row,:] + b1) . W2 + b2
// ---------------------------------------------------------------------------
__global__ __launch_bounds__(256) void mlp_tail_z(
    const float* __restrict__ hp, const float* __restrict__ b1,
    const float* __restrict__ w2, const float* __restrict__ b2,
    float* __restrict__ out)
{
  int row = blockIdx.x;
  int t   = threadIdx.x;
  float v = 0.f;
  #pragma unroll
  for (int q = 0; q < 2; q++) {
    int h = t + (q << 8);
    float s = 0.f;
    #pragma unroll
    for (int z = 0; z < Z_MLP; z++)
      s += hp[(size_t)z * (H_ * 512) + (size_t)row * H_ + h];
    s += b1[h];
    v += fmaxf(s, 0.f) * w2[h];
  }
  #pragma unroll
  for (int off = 32; off > 0; off >>= 1) v += __shfl_down(v, off, 64);
  __shared__ float red[4];
  if ((t & 63) == 0) red[t >> 6] = v;
  __syncthreads();
  if (t == 0) out[row] = red[0] + red[1] + red[2] + red[3] + b2[0];
}

// ---------------------------------------------------------------------------
// Per (b,i): sum z-planes of S, mask, row/col max, two softmaxes -> tw, dw
// ---------------------------------------------------------------------------
__global__ __launch_bounds__(64) void attn_weights(
    const float* __restrict__ Spart, const int* __restrict__ amt,
    const int* __restrict__ amd, float* __restrict__ tw, float* __restrict__ dw)
{
  __shared__ float Sm[36 * 37];
  __shared__ int   mtv[36], mdv[36];
  __shared__ float mrow[36], mcol[36];
  int bi = blockIdx.x;
  int b  = bi >> 5;
  int i  = bi & 31;
  int t  = threadIdx.x;
  if (t < 36) { mtv[t] = amt[b * 36 + t]; mdv[t] = amd[bi * 36 + t]; }
  __syncthreads();
  // 36 rows x 9 float4 per z-plane
  for (int f = t; f < 324; f += 64) {
    int x  = f / 9;
    int yq = (f - x * 9) << 2;
    size_t o = (((size_t)b * X_ + x) * NCOL + i * 36 + yq) >> 2;
    const float4* p = (const float4*)Spart;
    float4 v = p[o];
    #pragma unroll
    for (int z = 1; z < Z_S; z++) {
      float4 w2 = p[o + ((size_t)z * SP_PLANE >> 2)];
      v.x += w2.x; v.y += w2.y; v.z += w2.z; v.w += w2.w;
    }
    float* dst = &Sm[x * 37 + yq];
    bool mx = (mtv[x] != 0);
    dst[0] = (mx && mdv[yq + 0] != 0) ? v.x : -1e9f;
    dst[1] = (mx && mdv[yq + 1] != 0) ? v.y : -1e9f;
    dst[2] = (mx && mdv[yq + 2] != 0) ? v.z : -1e9f;
    dst[3] = (mx && mdv[yq + 3] != 0) ? v.w : -1e9f;
  }
  __syncthreads();
  if (t < 36) {
    float r = -INFINITY, c = -INFINITY;
    for (int k = 0; k < 36; k++) {
      r = fmaxf(r, Sm[t * 37 + k]);
      c = fmaxf(c, Sm[k * 37 + t]);
    }
    mrow[t] = r; mcol[t] = c;
  }
  __syncthreads();
  {
    float v = (t < 36) ? mrow[t] : -INFINITY;
    float m = v;
    #pragma unroll
    for (int off = 32; off > 0; off >>= 1) m = fmaxf(m, __shfl_xor(m, off, 64));
    float e = (t < 36) ? expf(v - m) : 0.f;
    float s = e;
    #pragma unroll
    for (int off = 32; off > 0; off >>= 1) s += __shfl_xor(s, off, 64);
    if (t < 36) tw[bi * 36 + t] = e / s;
  }
  {
    float v = (t < 36) ? mcol[t] : -INFINITY;
    float m = v;
    #pragma unroll
    for (int off = 32; off > 0; off >>= 1) m = fmaxf(m, __shfl_xor(m, off, 64));
    float e = (t < 36) ? expf(v - m) : 0.f;
    float s = e;
    #pragma unroll
    for (int off = 32; off > 0; off >>= 1) s += __shfl_xor(s, off, 64);
    if (t < 36) dw[bi * 36 + t] = e / s;
  }
}

// ---------------------------------------------------------------------------
// cat_att[bi] = [ sum_x tw[x]*att_t[b,x,:], sum_y dw[y]*att_d[bi,y,:] ]
// ---------------------------------------------------------------------------
__global__ __launch_bounds__(256) void wfeats(
    const float* __restrict__ attt, const float* __restrict__ attd,
    const float* __restrict__ tw, const float* __restrict__ dw,
    float* __restrict__ cat)
{
  __shared__ float twl[36], dwl[36];
  int bi = blockIdx.x, b = bi >> 5, t = threadIdx.x;
  if (t < 36) { twl[t] = tw[bi * 36 + t]; dwl[t] = dw[bi * 36 + t]; }
  __syncthreads();
  const float4* at4 = (const float4*)(attt + (size_t)b * X_ * D_);
  const float4* ad4 = (const float4*)(attd + (size_t)bi * X_ * D_);
  float4 t0 = make_float4(0, 0, 0, 0), t1 = t0, d0 = t0, d1 = t0;
  for (int x = 0; x < 36; x++) {
    float wt = twl[x], wd = dwl[x];
    float4 a  = at4[x * 512 + t];
    float4 a2 = at4[x * 512 + t + 256];
    float4 e  = ad4[x * 512 + t];
    float4 e2 = ad4[x * 512 + t + 256];
    t0.x = fmaf(wt, a.x, t0.x);  t0.y = fmaf(wt, a.y, t0.y);
    t0.z = fmaf(wt, a.z, t0.z);  t0.w = fmaf(wt, a.w, t0.w);
    t1.x = fmaf(wt, a2.x, t1.x); t1.y = fmaf(wt, a2.y, t1.y);
    t1.z = fmaf(wt, a2.z, t1.z); t1.w = fmaf(wt, a2.w, t1.w);
    d0.x = fmaf(wd, e.x, d0.x);  d0.y = fmaf(wd, e.y, d0.y);
    d0.z = fmaf(wd, e.z, d0.z);  d0.w = fmaf(wd, e.w, d0.w);
    d1.x = fmaf(wd, e2.x, d1.x); d1.y = fmaf(wd, e2.y, d1.y);
    d1.z = fmaf(wd, e2.z, d1.z); d1.w = fmaf(wd, e2.w, d1.w);
  }
  float4* c4 = (float4*)(cat + (size_t)bi * K2D);
  c4[t] = t0; c4[t + 256] = t1; c4[512 + t] = d0; c4[512 + t + 256] = d1;
}

// ---------------------------------------------------------------------------
// out[b,:] = log_softmax(sb + so) over N=32
// ---------------------------------------------------------------------------
__global__ __launch_bounds__(64) void lsm(
    const float* __restrict__ sb, const float* __restrict__ so,
    float* __restrict__ out)
{
  int b = blockIdx.x, t = threadIdx.x;
  float s = (t < 32) ? sb[b * 32 + t] + so[b * 32 + t] : -INFINITY;
  float m = s;
  #pragma unroll
  for (int off = 32; off > 0; off >>= 1) m = fmaxf(m, __shfl_xor(m, off, 64));
  float e = (t < 32) ? expf(s - m) : 0.f;
  float sum = e;
  #pragma unroll
  for (int off = 32; off > 0; off >>= 1) sum += __shfl_xor(sum, off, 64);
  if (t < 32) out[b * 32 + t] = s - m - logf(sum);
}

extern "C" void kernel_launch(void* const* d_in, const int* in_sizes, int n_in,
                              void* d_out, int out_size, void* d_ws, size_t ws_size,
                              hipStream_t stream)
{
  const float* fc_t  = (const float*)d_in[0];
  const float* fc_d  = (const float*)d_in[1];
  const float* att_t = (const float*)d_in[2];
  const float* att_d = (const float*)d_in[3];
  const int*   am_t  = (const int*)d_in[4];
  const int*   am_d  = (const int*)d_in[5];
  const float* W1    = (const float*)d_in[6];
  const float* b1    = (const float*)d_in[7];
  const float* W2    = (const float*)d_in[8];
  const float* b2    = (const float*)d_in[9];
  const float* Wbil  = (const float*)d_in[10];
  const float* oW1   = (const float*)d_in[11];
  const float* ob1   = (const float*)d_in[12];
  const float* oW2   = (const float*)d_in[13];
  const float* ob2   = (const float*)d_in[14];
  float* ws  = (float*)d_ws;
  float* out = (float*)d_out;

  // 1. base scorer hidden partials: HP1[z] = concat(fc_t, fc_d) @ W1
  gemm_mfma<<<dim3(4, 4, Z_MLP), 256, 0, stream>>>(fc_t, fc_d, W1, ws + O_A,
                                                   512, 512, 4096, 4096 / Z_MLP, 1);
  // 2. base scores
  mlp_tail_z<<<512, 256, 0, stream>>>(ws + O_A, b1, W2, b2, ws + O_SB);
  // 3. tproj partials: TPP[z] = att_t @ Wbil
  gemm_mfma<<<dim3(16, 5, Z_TP), 256, 0, stream>>>(att_t, nullptr, Wbil, ws + O_A,
                                                   576, 2048, 2048, 2048 / Z_TP, 0);
  reduce_tp<<<1152, 256, 0, stream>>>(ws + O_A, ws + O_B);
  // 4. inners partials
  sgemm36_mfma<<<dim3(9, 16, Z_S), 256, 0, stream>>>(ws + O_B, att_d, ws + O_A,
                                                     2048 / Z_S);
  // 5. attention weights
  attn_weights<<<512, 64, 0, stream>>>(ws + O_A, am_t, am_d, ws + O_TW, ws + O_DW);
  // 6. weighted features -> CAT
  wfeats<<<512, 256, 0, stream>>>(att_t, att_d, ws + O_TW, ws + O_DW, ws + O_B);
  // 7. object scorer hidden partials: HP2[z] = CAT @ oW1
  gemm_mfma<<<dim3(4, 4, Z_MLP), 256, 0, stream>>>(ws + O_B, nullptr, oW1, ws + O_A,
                                                   512, 512, 4096, 4096 / Z_MLP, 0);
  // 8. object scores
  mlp_tail_z<<<512, 256, 0, stream>>>(ws + O_A, ob1, oW2, ob2, ws + O_SO);
  // 9. final log_softmax
  lsm<<<16, 64, 0, stream>>>(ws + O_SB, ws + O_SO, out);
}

// Round 5
// 389.313 us; speedup vs baseline: 2.6282x; 1.0698x over previous
//
#include <hip/hip_runtime.h>
#include <math.h>

// Problem constants
#define D_   2048
#define H_   512
#define K2D  4096
#define X_   36
#define NCOL 1152   // N * Y = 32*36

// Split-K factors (partials + fused reduce; NO atomics anywhere)
#define Z_MLP 32    // kchunk 128
#define Z_TP  8     // kchunk 256
#define Z_S   4     // kchunk 512

// ws layout (float offsets), regions reused sequentially (~46 MB; ws >= 576MB)
//  A: HP1 (32x262144) -> TPP (8x1179648=9437184) -> SP (4x663552) -> HP2
//  B: TPROJ (1179648) -> CAT (2097152)
#define O_A   0u
#define O_B   9437184u
#define O_SB  11534336u
#define O_SO  11534848u

#define SP_PLANE 663552u   // 16*36*1152 per z-plane

typedef __attribute__((ext_vector_type(8))) short bf8_t;   // 8 bf16 (4 VGPRs)
typedef __attribute__((ext_vector_type(4))) float f4_t;    // MFMA accumulator

// fp32 -> bf16 round-to-nearest-even, and back
__device__ __forceinline__ unsigned short f2bf(float f) {
  unsigned u = __float_as_uint(f);
  unsigned r = u + 0x7FFFu + ((u >> 16) & 1u);
  return (unsigned short)(r >> 16);
}
__device__ __forceinline__ float bf2f(unsigned short h) {
  return __uint_as_float(((unsigned)h) << 16);
}

// LDS row stride 40 ushorts = 80 B: 16B-aligned rows; frag-read bank pattern
// is 2-way per phase (free per m136).
#define TSTR 40

// split x into bf16 hi/lo pair, store 8 k-contiguous to LDS
__device__ __forceinline__ void cvt8(unsigned short* Hp, unsigned short* Lp,
                                     float4 a, float4 b) {
  __align__(16) unsigned short h[8], l[8];
  float x[8] = {a.x, a.y, a.z, a.w, b.x, b.y, b.z, b.w};
  #pragma unroll
  for (int j = 0; j < 8; j++) {
    h[j] = f2bf(x[j]);
    l[j] = f2bf(x[j] - bf2f(h[j]));
  }
  *(bf8_t*)Hp = *(bf8_t*)&h[0];
  *(bf8_t*)Lp = *(bf8_t*)&l[0];
}

// ---------------------------------------------------------------------------
// Split-bf16 MFMA GEMM: Cpart[z] = A@B over z's K-chunk (fp32 in/out).
// 64x64 tile, 256 thr / 4 waves, wave tile 32x32 (2x2 frags of 16x16x32).
// All threads stage both A (2 float4) and B (8-scalar column gather);
// register prefetch double-buffer. amode=1: A rows = concat(fc_t[r/32], fc_d[r]).
// ---------------------------------------------------------------------------
__global__ __launch_bounds__(256, 4) void gemm_mfma64(
    const float* __restrict__ A, const float* __restrict__ A2,
    const float* __restrict__ Bm, float* __restrict__ Cpart,
    int M, int N, int K, int kchunk, int amode)
{
  __shared__ __align__(16) unsigned short AsH[64 * TSTR], AsL[64 * TSTR];
  __shared__ __align__(16) unsigned short BsH[64 * TSTR], BsL[64 * TSTR];
  const int t  = threadIdx.x;
  const int m0 = blockIdx.y << 6;
  const int n0 = blockIdx.x << 6;
  const int k0 = blockIdx.z * kchunk;
  const int kend = k0 + kchunk;
  const int w  = t >> 6;          // wave 0..3
  const int ln = t & 15;
  const int qd = (t >> 4) & 3;
  const int wm = (w >> 1) << 5;   // 0/32
  const int wn = (w & 1) << 5;    // 0/32
  // staging maps
  const int a_row = t >> 2;            // 0..63
  const int a_kq  = (t & 3) << 3;      // 0/8/16/24
  const int b_col = t & 63;
  const int b_kq  = (t >> 6) << 3;     // 0/8/16/24

  f4_t acc[2][2];
  #pragma unroll
  for (int i = 0; i < 2; i++)
    #pragma unroll
    for (int j = 0; j < 2; j++) acc[i][j] = (f4_t)0.f;

  float4 pa0, pa1;
  float  pb[8];

  auto loadA = [&](int kb) {
    int gr = m0 + a_row;
    int gk = kb + a_kq;              // multiple of 8; never straddles 2048
    pa0 = make_float4(0.f, 0.f, 0.f, 0.f);
    pa1 = pa0;
    if (gr < M) {
      const float* src;
      if (amode == 0) src = A + (size_t)gr * K + gk;
      else src = (gk < 2048) ? (A  + ((size_t)(gr >> 5) << 11) + gk)
                             : (A2 + ((size_t)gr << 11) + (gk - 2048));
      pa0 = *(const float4*)src;
      pa1 = *(const float4*)(src + 4);
    }
  };
  auto loadB = [&](int kb) {
    #pragma unroll
    for (int j = 0; j < 8; j++)
      pb[j] = Bm[(size_t)(kb + b_kq + j) * N + n0 + b_col];
  };

  loadA(k0); loadB(k0);

  for (int kb = k0; kb < kend; kb += 32) {
    __syncthreads();
    cvt8(&AsH[a_row * TSTR + a_kq], &AsL[a_row * TSTR + a_kq], pa0, pa1);
    cvt8(&BsH[b_col * TSTR + b_kq], &BsL[b_col * TSTR + b_kq],
         make_float4(pb[0], pb[1], pb[2], pb[3]),
         make_float4(pb[4], pb[5], pb[6], pb[7]));
    __syncthreads();
    if (kb + 32 < kend) { loadA(kb + 32); loadB(kb + 32); }
    bf8_t ah[2], al[2], bh[2], bl[2];
    #pragma unroll
    for (int fm = 0; fm < 2; fm++) {
      int r = (wm + (fm << 4) + ln) * TSTR + (qd << 3);
      ah[fm] = *(const bf8_t*)&AsH[r];
      al[fm] = *(const bf8_t*)&AsL[r];
    }
    #pragma unroll
    for (int fn = 0; fn < 2; fn++) {
      int r = (wn + (fn << 4) + ln) * TSTR + (qd << 3);
      bh[fn] = *(const bf8_t*)&BsH[r];
      bl[fn] = *(const bf8_t*)&BsL[r];
    }
    #pragma unroll
    for (int fm = 0; fm < 2; fm++)
      #pragma unroll
      for (int fn = 0; fn < 2; fn++) {
        acc[fm][fn] = __builtin_amdgcn_mfma_f32_16x16x32_bf16(ah[fm], bh[fn], acc[fm][fn], 0, 0, 0);
        acc[fm][fn] = __builtin_amdgcn_mfma_f32_16x16x32_bf16(ah[fm], bl[fn], acc[fm][fn], 0, 0, 0);
        acc[fm][fn] = __builtin_amdgcn_mfma_f32_16x16x32_bf16(al[fm], bh[fn], acc[fm][fn], 0, 0, 0);
      }
  }
  // C/D layout: row = qd*4+reg, col = ln  [m89-verified]
  float* Cz = Cpart + (size_t)blockIdx.z * M * N;
  #pragma unroll
  for (int fm = 0; fm < 2; fm++) {
    #pragma unroll
    for (int reg = 0; reg < 4; reg++) {
      int gr = m0 + wm + (fm << 4) + (qd << 2) + reg;
      if (gr < M) {
        #pragma unroll
        for (int fn = 0; fn < 2; fn++)
          Cz[(size_t)gr * N + n0 + wn + (fn << 4) + ln] = acc[fm][fn][reg];
      }
    }
  }
}

// ---------------------------------------------------------------------------
// tproj = sum_z TPP[z]   (576x2048 floats, Z_TP planes)
// ---------------------------------------------------------------------------
__global__ __launch_bounds__(256) void reduce_tp(
    const float* __restrict__ tpp, float* __restrict__ tproj)
{
  int idx = blockIdx.x * 256 + threadIdx.x;     // float4 index, 294912 total
  const float4* p = (const float4*)tpp;
  float4 a = p[idx];
  #pragma unroll
  for (int z = 1; z < Z_TP; z++) {
    float4 b = p[idx + (size_t)z * 294912];
    a.x += b.x; a.y += b.y; a.z += b.z; a.w += b.w;
  }
  ((float4*)tproj)[idx] = a;
}

// ---------------------------------------------------------------------------
// Spart[z][b][x][col] = tproj[b,x,:] . att_d[b,col,:] over z's K-chunk.
// 48x64 tile, 256 thr / 4 waves; wave w: all 48 rows (3 m-frags) x 16 cols.
// Both A and B are k-contiguous (float4 staging); register prefetch dbuf.
// ---------------------------------------------------------------------------
__global__ __launch_bounds__(256, 4) void sgemm36_mfma(
    const float* __restrict__ tproj, const float* __restrict__ attd,
    float* __restrict__ Spart, int kchunk)
{
  __shared__ __align__(16) unsigned short AsH[48 * TSTR], AsL[48 * TSTR];
  __shared__ __align__(16) unsigned short BsH[64 * TSTR], BsL[64 * TSTR];
  const int t  = threadIdx.x;
  const int n0 = blockIdx.x << 6;
  const int b  = blockIdx.y;
  const int k0 = blockIdx.z * kchunk;
  const int kend = k0 + kchunk;
  const int w  = t >> 6;
  const int ln = t & 15;
  const int qd = (t >> 4) & 3;
  const float* Ab = tproj + (size_t)b * X_ * D_;
  const float* Bb = attd  + (size_t)b * NCOL * D_;
  // staging maps: A by threads 0..191 (48 rows x 4 k-groups), B by all 256
  const int a_row = t >> 2;            // 0..63 (use <48)
  const int a_kq  = (t & 3) << 3;
  const int b_col = t & 63;
  const int b_kq  = (t >> 6) << 3;

  f4_t acc[3];
  #pragma unroll
  for (int i = 0; i < 3; i++) acc[i] = (f4_t)0.f;

  float4 pa0, pa1, pb0, pb1;

  auto loadA = [&](int kb) {
    pa0 = make_float4(0.f, 0.f, 0.f, 0.f);
    pa1 = pa0;
    if (a_row < X_) {
      const float* src = Ab + (size_t)a_row * D_ + kb + a_kq;
      pa0 = *(const float4*)src;
      pa1 = *(const float4*)(src + 4);
    }
  };
  auto loadB = [&](int kb) {
    const float* src = Bb + (size_t)(n0 + b_col) * D_ + kb + b_kq;
    pb0 = *(const float4*)src;
    pb1 = *(const float4*)(src + 4);
  };

  loadA(k0); loadB(k0);

  for (int kb = k0; kb < kend; kb += 32) {
    __syncthreads();
    if (a_row < 48)
      cvt8(&AsH[a_row * TSTR + a_kq], &AsL[a_row * TSTR + a_kq], pa0, pa1);
    cvt8(&BsH[b_col * TSTR + b_kq], &BsL[b_col * TSTR + b_kq], pb0, pb1);
    __syncthreads();
    if (kb + 32 < kend) { loadA(kb + 32); loadB(kb + 32); }
    bf8_t ah[3], al[3], bh, bl;
    #pragma unroll
    for (int fm = 0; fm < 3; fm++) {
      int r = ((fm << 4) + ln) * TSTR + (qd << 3);
      ah[fm] = *(const bf8_t*)&AsH[r];
      al[fm] = *(const bf8_t*)&AsL[r];
    }
    {
      int r = ((w << 4) + ln) * TSTR + (qd << 3);
      bh = *(const bf8_t*)&BsH[r];
      bl = *(const bf8_t*)&BsL[r];
    }
    #pragma unroll
    for (int fm = 0; fm < 3; fm++) {
      acc[fm] = __builtin_amdgcn_mfma_f32_16x16x32_bf16(ah[fm], bh, acc[fm], 0, 0, 0);
      acc[fm] = __builtin_amdgcn_mfma_f32_16x16x32_bf16(ah[fm], bl, acc[fm], 0, 0, 0);
      acc[fm] = __builtin_amdgcn_mfma_f32_16x16x32_bf16(al[fm], bh, acc[fm], 0, 0, 0);
    }
  }
  float* Sz = Spart + (size_t)blockIdx.z * SP_PLANE + (size_t)b * X_ * NCOL;
  #pragma unroll
  for (int fm = 0; fm < 3; fm++) {
    #pragma unroll
    for (int reg = 0; reg < 4; reg++) {
      int x = (fm << 4) + (qd << 2) + reg;
      if (x < X_)
        Sz[(size_t)x * NCOL + n0 + (w << 4) + ln] = acc[fm][reg];
    }
  }
}

// ---------------------------------------------------------------------------
// scores[row] = relu(sum_z hp[z][row,:] + b1) . W2 + b2
// ---------------------------------------------------------------------------
__global__ __launch_bounds__(256) void mlp_tail_z(
    const float* __restrict__ hp, const float* __restrict__ b1,
    const float* __restrict__ w2, const float* __restrict__ b2,
    float* __restrict__ out)
{
  int row = blockIdx.x;
  int t   = threadIdx.x;
  float v = 0.f;
  #pragma unroll
  for (int q = 0; q < 2; q++) {
    int h = t + (q << 8);
    float s = 0.f;
    #pragma unroll
    for (int z = 0; z < Z_MLP; z++)
      s += hp[(size_t)z * (H_ * 512) + (size_t)row * H_ + h];
    s += b1[h];
    v += fmaxf(s, 0.f) * w2[h];
  }
  #pragma unroll
  for (int off = 32; off > 0; off >>= 1) v += __shfl_down(v, off, 64);
  __shared__ float red[4];
  if ((t & 63) == 0) red[t >> 6] = v;
  __syncthreads();
  if (t == 0) out[row] = red[0] + red[1] + red[2] + red[3] + b2[0];
}

// ---------------------------------------------------------------------------
// Per (b,i), fused: sum SP z-planes + mask + row/col max + two softmaxes,
// then cat_att[bi] = [sum_x tw[x]*att_t[b,x,:], sum_y dw[y]*att_d[bi,y,:]].
// 256 threads.
// ---------------------------------------------------------------------------
__global__ __launch_bounds__(256) void attn_fused(
    const float* __restrict__ Spart, const int* __restrict__ amt,
    const int* __restrict__ amd, const float* __restrict__ attt,
    const float* __restrict__ attd, float* __restrict__ cat)
{
  __shared__ float Sm[36 * 37];
  __shared__ int   mtv[36], mdv[36];
  __shared__ float mrow[36], mcol[36], twl[36], dwl[36];
  int bi = blockIdx.x;
  int b  = bi >> 5;
  int i  = bi & 31;
  int t  = threadIdx.x;
  if (t < 36) { mtv[t] = amt[b * 36 + t]; mdv[t] = amd[bi * 36 + t]; }
  __syncthreads();
  // 36 rows x 9 float4 per z-plane
  for (int f = t; f < 324; f += 256) {
    int x  = f / 9;
    int yq = (f - x * 9) << 2;
    size_t o = (((size_t)b * X_ + x) * NCOL + i * 36 + yq) >> 2;
    const float4* p = (const float4*)Spart;
    float4 v = p[o];
    #pragma unroll
    for (int z = 1; z < Z_S; z++) {
      float4 wv = p[o + ((size_t)z * SP_PLANE >> 2)];
      v.x += wv.x; v.y += wv.y; v.z += wv.z; v.w += wv.w;
    }
    float* dst = &Sm[x * 37 + yq];
    bool mx = (mtv[x] != 0);
    dst[0] = (mx && mdv[yq + 0] != 0) ? v.x : -1e9f;
    dst[1] = (mx && mdv[yq + 1] != 0) ? v.y : -1e9f;
    dst[2] = (mx && mdv[yq + 2] != 0) ? v.z : -1e9f;
    dst[3] = (mx && mdv[yq + 3] != 0) ? v.w : -1e9f;
  }
  __syncthreads();
  if (t < 36) {
    float r = -INFINITY, c = -INFINITY;
    for (int k = 0; k < 36; k++) {
      r = fmaxf(r, Sm[t * 37 + k]);
      c = fmaxf(c, Sm[k * 37 + t]);
    }
    mrow[t] = r; mcol[t] = c;
  }
  __syncthreads();
  if (t < 64) {           // wave 0: softmax over row-max -> tw
    float v = (t < 36) ? mrow[t] : -INFINITY;
    float m = v;
    #pragma unroll
    for (int off = 32; off > 0; off >>= 1) m = fmaxf(m, __shfl_xor(m, off, 64));
    float e = (t < 36) ? expf(v - m) : 0.f;
    float s = e;
    #pragma unroll
    for (int off = 32; off > 0; off >>= 1) s += __shfl_xor(s, off, 64);
    if (t < 36) twl[t] = e / s;
  } else if (t < 128) {   // wave 1: softmax over col-max -> dw (concurrent)
    int l = t - 64;
    float v = (l < 36) ? mcol[l] : -INFINITY;
    float m = v;
    #pragma unroll
    for (int off = 32; off > 0; off >>= 1) m = fmaxf(m, __shfl_xor(m, off, 64));
    float e = (l < 36) ? expf(v - m) : 0.f;
    float s = e;
    #pragma unroll
    for (int off = 32; off > 0; off >>= 1) s += __shfl_xor(s, off, 64);
    if (l < 36) dwl[l] = e / s;
  }
  __syncthreads();
  // weighted features -> cat
  const float4* at4 = (const float4*)(attt + (size_t)b * X_ * D_);
  const float4* ad4 = (const float4*)(attd + (size_t)bi * X_ * D_);
  float4 t0 = make_float4(0, 0, 0, 0), t1 = t0, d0 = t0, d1 = t0;
  for (int x = 0; x < 36; x++) {
    float wt = twl[x], wd = dwl[x];
    float4 a  = at4[x * 512 + t];
    float4 a2 = at4[x * 512 + t + 256];
    float4 e  = ad4[x * 512 + t];
    float4 e2 = ad4[x * 512 + t + 256];
    t0.x = fmaf(wt, a.x, t0.x);  t0.y = fmaf(wt, a.y, t0.y);
    t0.z = fmaf(wt, a.z, t0.z);  t0.w = fmaf(wt, a.w, t0.w);
    t1.x = fmaf(wt, a2.x, t1.x); t1.y = fmaf(wt, a2.y, t1.y);
    t1.z = fmaf(wt, a2.z, t1.z); t1.w = fmaf(wt, a2.w, t1.w);
    d0.x = fmaf(wd, e.x, d0.x);  d0.y = fmaf(wd, e.y, d0.y);
    d0.z = fmaf(wd, e.z, d0.z);  d0.w = fmaf(wd, e.w, d0.w);
    d1.x = fmaf(wd, e2.x, d1.x); d1.y = fmaf(wd, e2.y, d1.y);
    d1.z = fmaf(wd, e2.z, d1.z); d1.w = fmaf(wd, e2.w, d1.w);
  }
  float4* c4 = (float4*)(cat + (size_t)bi * K2D);
  c4[t] = t0; c4[t + 256] = t1; c4[512 + t] = d0; c4[512 + t + 256] = d1;
}

// ---------------------------------------------------------------------------
// out[b,:] = log_softmax(sb + so) over N=32
// ---------------------------------------------------------------------------
__global__ __launch_bounds__(64) void lsm(
    const float* __restrict__ sb, const float* __restrict__ so,
    float* __restrict__ out)
{
  int b = blockIdx.x, t = threadIdx.x;
  float s = (t < 32) ? sb[b * 32 + t] + so[b * 32 + t] : -INFINITY;
  float m = s;
  #pragma unroll
  for (int off = 32; off > 0; off >>= 1) m = fmaxf(m, __shfl_xor(m, off, 64));
  float e = (t < 32) ? expf(s - m) : 0.f;
  float sum = e;
  #pragma unroll
  for (int off = 32; off > 0; off >>= 1) sum += __shfl_xor(sum, off, 64);
  if (t < 32) out[b * 32 + t] = s - m - logf(sum);
}

extern "C" void kernel_launch(void* const* d_in, const int* in_sizes, int n_in,
                              void* d_out, int out_size, void* d_ws, size_t ws_size,
                              hipStream_t stream)
{
  const float* fc_t  = (const float*)d_in[0];
  const float* fc_d  = (const float*)d_in[1];
  const float* att_t = (const float*)d_in[2];
  const float* att_d = (const float*)d_in[3];
  const int*   am_t  = (const int*)d_in[4];
  const int*   am_d  = (const int*)d_in[5];
  const float* W1    = (const float*)d_in[6];
  const float* b1    = (const float*)d_in[7];
  const float* W2    = (const float*)d_in[8];
  const float* b2    = (const float*)d_in[9];
  const float* Wbil  = (const float*)d_in[10];
  const float* oW1   = (const float*)d_in[11];
  const float* ob1   = (const float*)d_in[12];
  const float* oW2   = (const float*)d_in[13];
  const float* ob2   = (const float*)d_in[14];
  float* ws  = (float*)d_ws;
  float* out = (float*)d_out;

  // 1. base scorer hidden partials: HP1[z] = concat(fc_t, fc_d) @ W1
  gemm_mfma64<<<dim3(8, 8, Z_MLP), 256, 0, stream>>>(fc_t, fc_d, W1, ws + O_A,
                                                     512, 512, 4096, 4096 / Z_MLP, 1);
  // 2. base scores
  mlp_tail_z<<<512, 256, 0, stream>>>(ws + O_A, b1, W2, b2, ws + O_SB);
  // 3. tproj partials: TPP[z] = att_t @ Wbil
  gemm_mfma64<<<dim3(32, 9, Z_TP), 256, 0, stream>>>(att_t, nullptr, Wbil, ws + O_A,
                                                     576, 2048, 2048, 2048 / Z_TP, 0);
  reduce_tp<<<1152, 256, 0, stream>>>(ws + O_A, ws + O_B);
  // 4. inners partials
  sgemm36_mfma<<<dim3(18, 16, Z_S), 256, 0, stream>>>(ws + O_B, att_d, ws + O_A,
                                                      2048 / Z_S);
  // 5. attention weights + weighted features -> CAT (fused)
  attn_fused<<<512, 256, 0, stream>>>(ws + O_A, am_t, am_d, att_t, att_d, ws + O_B);
  // 6. object scorer hidden partials: HP2[z] = CAT @ oW1
  gemm_mfma64<<<dim3(8, 8, Z_MLP), 256, 0, stream>>>(ws + O_B, nullptr, oW1, ws + O_A,
                                                     512, 512, 4096, 4096 / Z_MLP, 0);
  // 7. object scores
  mlp_tail_z<<<512, 256, 0, stream>>>(ws + O_A, ob1, oW2, ob2, ws + O_SO);
  // 8. final log_softmax
  lsm<<<16, 64, 0, stream>>>(ws + O_SB, ws + O_SO, out);
}